// Round 11
// baseline (2190.160 us; speedup 1.0000x reference)
//
#include <hip/hip_runtime.h>
#include <hip/hip_bf16.h>

#define NN 50000
#define DIN 256
#define HD 512
#define DCAT 768
#define DMID 1024
#define DSUM 1536
#define DOUT 256
#define CH 19200
#define LN_EPS 1e-5f

typedef __attribute__((ext_vector_type(8))) short short8;
typedef __attribute__((ext_vector_type(4))) float f32x4;
typedef __attribute__((ext_vector_type(2))) float f32x2;

__device__ __forceinline__ unsigned short f2b(float f) {
  unsigned int u = __float_as_uint(f);
  u += 0x7FFF + ((u >> 16) & 1);   // round-to-nearest-even
  return (unsigned short)(u >> 16);
}
__device__ __forceinline__ float b2f(unsigned short s) {
  return __uint_as_float(((unsigned int)s) << 16);
}
__device__ __forceinline__ void splitbf(float v, unsigned short& hi, unsigned short& lo) {
  hi = f2b(v);
  lo = f2b(v - b2f(hi));
}
// fp8 e4m3 encode (hardware, saturating)
__device__ __forceinline__ unsigned char f2e4m3(float v) {
  return (unsigned char)(__builtin_amdgcn_cvt_pk_fp8_f32(v, v, 0, false) & 0xff);
}

// ---------------- diagnostic fill ----------------
__global__ void sentinel_fill(float* __restrict__ out, long n, float v) {
  for (long i = (long)blockIdx.x * blockDim.x + threadIdx.x; i < n;
       i += (long)gridDim.x * blockDim.x)
    out[i] = v;
}

// ---------------- casts / splits ----------------
// x -> bf16 hi/lo + fp8 in one pass
__global__ void cast_split8_kernel(const float* __restrict__ in,
                                   unsigned short* __restrict__ oh,
                                   unsigned short* __restrict__ ol,
                                   unsigned char* __restrict__ o8, long n4) {
  for (long i = (long)blockIdx.x * blockDim.x + threadIdx.x; i < n4;
       i += (long)gridDim.x * blockDim.x) {
    float4 v = ((const float4*)in)[i];
    ushort4 h, l;
    splitbf(v.x, h.x, l.x); splitbf(v.y, h.y, l.y);
    splitbf(v.z, h.z, l.z); splitbf(v.w, h.w, l.w);
    ((ushort4*)oh)[i] = h;
    ((ushort4*)ol)[i] = l;
    unsigned int r = __builtin_amdgcn_cvt_pk_fp8_f32(v.x, v.y, 0, false);
    r = __builtin_amdgcn_cvt_pk_fp8_f32(v.z, v.w, r, true);
    ((unsigned int*)o8)[i] = r;
  }
}

// in: [K][N] f32 -> out hi(/lo): [N][K] bf16  (K,N multiples of 32). blockIdx.z = matrix idx
template <bool SPLIT>
__global__ void cast_transpose_kernel(const float* __restrict__ in,
                                      unsigned short* __restrict__ oh,
                                      unsigned short* __restrict__ ol, int K, int N) {
  const float* src = in + (long)blockIdx.z * K * N;
  unsigned short* dh = oh + (long)blockIdx.z * K * N;
  unsigned short* dl = SPLIT ? ol + (long)blockIdx.z * K * N : nullptr;
  __shared__ unsigned short th[32][33];
  __shared__ unsigned short tl[SPLIT ? 32 : 1][33];
  int bk = blockIdx.x * 32, bn = blockIdx.y * 32;
  int tx = threadIdx.x & 31, ty = threadIdx.x >> 5;
#pragma unroll
  for (int i = ty; i < 32; i += 8) {
    float v = src[(long)(bk + i) * N + bn + tx];
    if (SPLIT) {
      unsigned short h, l;
      splitbf(v, h, l);
      th[i][tx] = h; tl[i][tx] = l;
    } else {
      th[i][tx] = f2b(v);
    }
  }
  __syncthreads();
#pragma unroll
  for (int i = ty; i < 32; i += 8) {
    dh[(long)(bn + i) * K + bk + tx] = th[tx][i];
    if (SPLIT) dl[(long)(bn + i) * K + bk + tx] = tl[tx][i];
  }
}

// ---------------- CSR build ----------------
__global__ void deg_kernel(const int* __restrict__ dst, int E, int* __restrict__ rowptr) {
  int i = blockIdx.x * blockDim.x + threadIdx.x;
  if (i < E) atomicAdd(&rowptr[dst[i] + 1], 1);
}

__global__ void scan_block(int* __restrict__ data, int n, int* __restrict__ sums) {
  __shared__ int tmp[2][256];
  int i = blockIdx.x * 256 + threadIdx.x;
  int v = (i < n) ? data[i] : 0;
  int pp = 0;
  tmp[0][threadIdx.x] = v;
  __syncthreads();
#pragma unroll
  for (int off = 1; off < 256; off <<= 1) {
    int t2 = tmp[pp][threadIdx.x];
    if (threadIdx.x >= off) t2 += tmp[pp][threadIdx.x - off];
    tmp[pp ^ 1][threadIdx.x] = t2;
    pp ^= 1;
    __syncthreads();
  }
  if (i < n) data[i] = tmp[pp][threadIdx.x];
  if (threadIdx.x == 255) sums[blockIdx.x] = tmp[pp][255];
}

__global__ void scan_add(int* __restrict__ data, int n, const int* __restrict__ sums) {
  int i = blockIdx.x * 256 + threadIdx.x;
  if (blockIdx.x > 0 && i < n) data[i] += sums[blockIdx.x - 1];
}

__global__ void fill_kernel(const int* __restrict__ src, const int* __restrict__ dst, int E,
                            const int* __restrict__ rowptr, int* __restrict__ cursor,
                            int* __restrict__ cols) {
  int i = blockIdx.x * blockDim.x + threadIdx.x;
  if (i < E) {
    int r = dst[i];
    int p = rowptr[r] + atomicAdd(&cursor[r], 1);
    cols[p] = src[i];
  }
}

// ---------------- aggregation (wave-per-node; fp8 neighbor gather; round-8 proven) ----------------
// xpart[i,:] = bf16(xb_i + sum_j x8_j)  (own bf16, neighbors fp8 256B/row)
__global__ void agg_x_kernel(const unsigned short* __restrict__ xb,
                             const unsigned char* __restrict__ x8,
                             const int* __restrict__ rowptr,
                             const int* __restrict__ cols,
                             unsigned short* __restrict__ xpart) {
  int node = blockIdx.x * 4 + (threadIdx.x >> 6);
  int lane = threadIdx.x & 63;
  ushort4 own = *((const ushort4*)(xb + (long)node * DIN) + lane);
  float s0 = b2f(own.x), s1 = b2f(own.y), s2 = b2f(own.z), s3 = b2f(own.w);
  int e0 = rowptr[node], e1 = rowptr[node + 1];
  int p = e0;
#define XACC(w)                                                   \
  {                                                               \
    f32x2 t0 = __builtin_amdgcn_cvt_pk_f32_fp8((w), false);       \
    f32x2 t1 = __builtin_amdgcn_cvt_pk_f32_fp8((w), true);        \
    s0 += t0.x; s1 += t0.y; s2 += t1.x; s3 += t1.y;               \
  }
  for (; p + 3 < e1; p += 4) {
    int j0 = cols[p], j1 = cols[p + 1], j2 = cols[p + 2], j3 = cols[p + 3];
    unsigned int a = *((const unsigned int*)(x8 + (long)j0 * DIN) + lane);
    unsigned int b = *((const unsigned int*)(x8 + (long)j1 * DIN) + lane);
    unsigned int c = *((const unsigned int*)(x8 + (long)j2 * DIN) + lane);
    unsigned int d = *((const unsigned int*)(x8 + (long)j3 * DIN) + lane);
    XACC(a); XACC(b); XACC(c); XACC(d);
  }
  for (; p < e1; p++) {
    unsigned int a = *((const unsigned int*)(x8 + (long)cols[p] * DIN) + lane);
    XACC(a);
  }
#undef XACC
  ushort4 o;
  o.x = f2b(s0); o.y = f2b(s1); o.z = f2b(s2); o.w = f2b(s3);
  *((ushort4*)(xpart + (long)node * DIN) + lane) = o;
}

// hpart[i,:] = bf16(h_i + sum_j h8_j)  (own bf16 1KB, neighbors fp8 512B/row)
__global__ void agg_h_kernel(const unsigned short* __restrict__ h,
                             const unsigned char* __restrict__ h8,
                             const int* __restrict__ rowptr, const int* __restrict__ cols,
                             unsigned short* __restrict__ hpart) {
  int node = blockIdx.x * 4 + (threadIdx.x >> 6);
  int lane = threadIdx.x & 63;
  short8 own = *((const short8*)(h + (long)node * HD) + lane);
  float s[8];
#pragma unroll
  for (int q = 0; q < 8; q++) s[q] = b2f((unsigned short)own[q]);
  int e0 = rowptr[node], e1 = rowptr[node + 1];
  int p = e0;
#define HACC(w)                                                   \
  {                                                               \
    f32x2 t0 = __builtin_amdgcn_cvt_pk_f32_fp8((w).x, false);     \
    f32x2 t1 = __builtin_amdgcn_cvt_pk_f32_fp8((w).x, true);      \
    f32x2 t2 = __builtin_amdgcn_cvt_pk_f32_fp8((w).y, false);     \
    f32x2 t3 = __builtin_amdgcn_cvt_pk_f32_fp8((w).y, true);      \
    s[0] += t0.x; s[1] += t0.y; s[2] += t1.x; s[3] += t1.y;       \
    s[4] += t2.x; s[5] += t2.y; s[6] += t3.x; s[7] += t3.y;       \
  }
  for (; p + 3 < e1; p += 4) {
    int j0 = cols[p], j1 = cols[p + 1], j2 = cols[p + 2], j3 = cols[p + 3];
    uint2 a = *((const uint2*)(h8 + (long)j0 * HD) + lane);
    uint2 b = *((const uint2*)(h8 + (long)j1 * HD) + lane);
    uint2 c = *((const uint2*)(h8 + (long)j2 * HD) + lane);
    uint2 d = *((const uint2*)(h8 + (long)j3 * HD) + lane);
    HACC(a); HACC(b); HACC(c); HACC(d);
  }
  for (; p < e1; p++) {
    uint2 a = *((const uint2*)(h8 + (long)cols[p] * HD) + lane);
    HACC(a);
  }
#undef HACC
  short8 o;
#pragma unroll
  for (int q = 0; q < 8; q++) o[q] = (short)f2b(s[q]);
  *((short8*)(hpart + (long)node * HD) + lane) = o;
}

// ---------------- LayerNorm + leaky on bf16 rows of width 1024 (in place) ----------------
__global__ void ln_leaky_kernel(unsigned short* __restrict__ arr,
                                const float* __restrict__ gamma,
                                const float* __restrict__ beta) {
  int row = blockIdx.x, t = threadIdx.x;
  unsigned short* p = arr + (long)row * DMID;
  ushort4 u = ((const ushort4*)p)[t];
  float v0 = b2f(u.x), v1 = b2f(u.y), v2 = b2f(u.z), v3 = b2f(u.w);
  float s = v0 + v1 + v2 + v3;
  float sq = v0 * v0 + v1 * v1 + v2 * v2 + v3 * v3;
#pragma unroll
  for (int off = 32; off >= 1; off >>= 1) {
    s += __shfl_down(s, off, 64);
    sq += __shfl_down(sq, off, 64);
  }
  __shared__ float red[8];
  int w = t >> 6, lane = t & 63;
  if (lane == 0) { red[w] = s; red[4 + w] = sq; }
  __syncthreads();
  s = red[0] + red[1] + red[2] + red[3];
  sq = red[4] + red[5] + red[6] + red[7];
  float mean = s * (1.f / DMID);
  float var = sq * (1.f / DMID) - mean * mean;
  float rstd = rsqrtf(var + LN_EPS);
  float4 gv = ((const float4*)gamma)[t];
  float4 bv = ((const float4*)beta)[t];
  float o0 = (v0 - mean) * rstd * gv.x + bv.x;
  float o1 = (v1 - mean) * rstd * gv.y + bv.y;
  float o2 = (v2 - mean) * rstd * gv.z + bv.z;
  float o3 = (v3 - mean) * rstd * gv.w + bv.w;
  o0 = o0 > 0.f ? o0 : 0.1f * o0;
  o1 = o1 > 0.f ? o1 : 0.1f * o1;
  o2 = o2 > 0.f ? o2 : 0.1f * o2;
  o3 = o3 > 0.f ? o3 : 0.1f * o3;
  ushort4 ou;
  ou.x = f2b(o0); ou.y = f2b(o1); ou.z = f2b(o2); ou.w = f2b(o3);
  ((ushort4*)p)[t] = ou;
}

#define GLD16(src, dst)                                                          \
  __builtin_amdgcn_global_load_lds(                                              \
      (const __attribute__((address_space(1))) void*)(src),                      \
      (__attribute__((address_space(3))) void*)(dst), 16, 0, 0)

// ---------------- 1-pass MFMA GEMM, double-buffered single-barrier K-loop ----------------
// C[M,N] = A[M,K] * Bt[N,K]^T + bias. 128x128 tile, BK=64, 4 waves (2x2).
// Per iter: issue next tile's global_load_lds BEFORE computing current tile;
// one __syncthreads() per iter (its vmcnt(0) drain lands after the MFMA phase).
// Race-free: stages write buf[cur^1], reads hit buf[cur]; overwrite only after barrier.
template <bool ACT, bool W8, int BK>
__launch_bounds__(256, 2)
__global__ void gemm1p(const unsigned short* __restrict__ Ah,
                       const unsigned short* __restrict__ A2h,
                       int lda, int lda2, int ksplit,
                       const unsigned short* __restrict__ Bh,
                       int ldb, const float* __restrict__ bias,
                       unsigned short* __restrict__ Chi,
                       unsigned char* __restrict__ C8,
                       int ldc, int M, int K) {
  __shared__ __align__(16) unsigned short Ash[2][128 * BK];
  __shared__ __align__(16) unsigned short Bsh[2][128 * BK];
  const int t = threadIdx.x;
  const int bm = blockIdx.x, bn = blockIdx.y;
  const int l = t & 63;
  const int w = t >> 6;
  const int wm = w >> 1, wn = w & 1;
  const int lrow = l & 15, lk = (l >> 4) * 8;

  f32x4 acc[4][4] = {};

  const int arow0 = bm * 128;
  const int brow0 = bn * 128;

  auto STAGE = [&](int buf, int k0) {
    const bool first = k0 < ksplit;
    const unsigned short* Abase = first ? Ah : A2h;
    const int acol = first ? k0 : (k0 - ksplit);
    const int alda = first ? lda : lda2;
#pragma unroll
    for (int it = 0; it < BK / 16; it++) {
      int c = t + it * 256;
      int row = c / (BK / 8);
      int sk = (c % (BK / 8)) * 8;
      int ar = arow0 + row;
      if (ar >= M) ar = M - 1;
      int ldst = row * BK + sk;     // == 8*c elems: lane*16B from wave-uniform base
      GLD16(Abase + (long)ar * alda + acol + sk, Ash[buf] + ldst);
      GLD16(Bh + (long)(brow0 + row) * ldb + k0 + sk, Bsh[buf] + ldst);
    }
  };

  const int nt = K / BK;
  STAGE(0, 0);
  __syncthreads();
  int cur = 0;
  for (int tk = 0; tk < nt; tk++) {
    if (tk + 1 < nt) STAGE(cur ^ 1, (tk + 1) * BK);
#pragma unroll
    for (int kk = 0; kk < BK / 32; kk++) {
      short8 ah[4], bh[4];
#pragma unroll
      for (int m = 0; m < 4; m++)
        ah[m] = *(const short8*)(Ash[cur] + (wm * 64 + m * 16 + lrow) * BK + kk * 32 + lk);
#pragma unroll
      for (int n = 0; n < 4; n++)
        bh[n] = *(const short8*)(Bsh[cur] + (wn * 64 + n * 16 + lrow) * BK + kk * 32 + lk);
#pragma unroll
      for (int m = 0; m < 4; m++)
#pragma unroll
        for (int n = 0; n < 4; n++)
          acc[m][n] = __builtin_amdgcn_mfma_f32_16x16x32_bf16(ah[m], bh[n], acc[m][n], 0, 0, 0);
    }
    __syncthreads();
    cur ^= 1;
  }

  const int orow0 = bm * 128 + wm * 64 + (l >> 4) * 4;
  const int ocol0 = bn * 128 + wn * 64 + lrow;
#pragma unroll
  for (int n = 0; n < 4; n++) {
    int gc = ocol0 + n * 16;
    float bv = bias[gc];
#pragma unroll
    for (int m = 0; m < 4; m++) {
#pragma unroll
      for (int ri = 0; ri < 4; ri++) {
        int gr = orow0 + m * 16 + ri;
        if (gr < M) {
          float v = acc[m][n][ri] + bv;
          if constexpr (ACT) v = v > 0.f ? v : 0.1f * v;
          Chi[(long)gr * ldc + gc] = f2b(v);
          if constexpr (W8) C8[(long)gr * ldc + gc] = f2e4m3(v);
        }
      }
    }
  }
}

// ---------------- multi-pass MFMA GEMM (in_proj / out): unchanged round-10 structure ----------------
template <int WMODE, bool AL, bool BL, bool ACC, bool W8, int OCC, int BK>
__launch_bounds__(256, OCC)
__global__ void gemmx(const unsigned short* __restrict__ Ah,
                      const unsigned short* __restrict__ Al,
                      int lda,
                      const unsigned short* __restrict__ Bh,
                      const unsigned short* __restrict__ Bl,
                      int ldb, const float* __restrict__ bias,
                      float* __restrict__ Cf,
                      unsigned short* __restrict__ Chi,
                      unsigned char* __restrict__ C8,
                      int ldc, int M, int K) {
  __shared__ __align__(16) unsigned short Ash[128 * BK];
  __shared__ __align__(16) unsigned short Asl[AL ? 128 * BK : 16];
  __shared__ __align__(16) unsigned short Bsh[128 * BK];
  __shared__ __align__(16) unsigned short Bsl[BL ? 128 * BK : 16];
  const int t = threadIdx.x;
  const int bm = blockIdx.x, bn = blockIdx.y;
  const int l = t & 63;
  const int w = t >> 6;
  const int wm = w >> 1, wn = w & 1;
  const int lrow = l & 15, lk = (l >> 4) * 8;

  f32x4 acc[4][4] = {};

  const int arow0 = bm * 128;
  const int brow0 = bn * 128;

  for (int k0 = 0; k0 < K; k0 += BK) {
    __syncthreads();
#pragma unroll
    for (int it = 0; it < BK / 16; it++) {
      int c = t + it * 256;
      int row = c / (BK / 8);
      int sk = (c % (BK / 8)) * 8;
      int ar = arow0 + row;
      if (ar >= M) ar = M - 1;
      long boff = (long)(brow0 + row) * ldb + k0 + sk;
      int ldst = row * BK + sk;
      GLD16(Ah + (long)ar * lda + k0 + sk, Ash + ldst);
      if (AL) GLD16(Al + (long)ar * lda + k0 + sk, Asl + ldst);
      GLD16(Bh + boff, Bsh + ldst);
      if (BL) GLD16(Bl + boff, Bsl + ldst);
    }
    __syncthreads();
#pragma unroll
    for (int kk = 0; kk < BK / 32; kk++) {
      short8 ah[4], al4[4], bh[4], bl4[4];
#pragma unroll
      for (int m = 0; m < 4; m++) {
        int ro = (wm * 64 + m * 16 + lrow) * BK + kk * 32 + lk;
        ah[m] = *(const short8*)(Ash + ro);
        if (AL) al4[m] = *(const short8*)(Asl + ro);
      }
#pragma unroll
      for (int n = 0; n < 4; n++) {
        int ro = (wn * 64 + n * 16 + lrow) * BK + kk * 32 + lk;
        bh[n] = *(const short8*)(Bsh + ro);
        if (BL) bl4[n] = *(const short8*)(Bsl + ro);
      }
#pragma unroll
      for (int m = 0; m < 4; m++)
#pragma unroll
        for (int n = 0; n < 4; n++) {
          acc[m][n] = __builtin_amdgcn_mfma_f32_16x16x32_bf16(ah[m], bh[n], acc[m][n], 0, 0, 0);
          if (BL)
            acc[m][n] = __builtin_amdgcn_mfma_f32_16x16x32_bf16(ah[m], bl4[n], acc[m][n], 0, 0, 0);
          if (AL)
            acc[m][n] = __builtin_amdgcn_mfma_f32_16x16x32_bf16(al4[m], bh[n], acc[m][n], 0, 0, 0);
        }
    }
  }

  const int orow0 = bm * 128 + wm * 64 + (l >> 4) * 4;
  const int ocol0 = bn * 128 + wn * 64 + lrow;
#pragma unroll
  for (int n = 0; n < 4; n++) {
    int gc = ocol0 + n * 16;
    float bv;
    if constexpr (ACC) bv = 0.f; else bv = bias[gc];
#pragma unroll
    for (int m = 0; m < 4; m++) {
#pragma unroll
      for (int ri = 0; ri < 4; ri++) {
        int gr = orow0 + m * 16 + ri;
        if (gr < M) {
          float v = acc[m][n][ri] + bv;
          if constexpr (ACC) v += Cf[(long)gr * ldc + gc];
          if constexpr (WMODE == 0) {
            Cf[(long)gr * ldc + gc] = v;
          } else {
            Chi[(long)gr * ldc + gc] = f2b(v);
            if constexpr (W8) C8[(long)gr * ldc + gc] = f2e4m3(v);
          }
        }
      }
    }
  }
}

// ---------------- host ----------------
extern "C" void kernel_launch(void* const* d_in, const int* in_sizes, int n_in,
                              void* d_out, int out_size, void* d_ws, size_t ws_size,
                              hipStream_t stream) {
  const float* x = (const float*)d_in[0];
  const int* ei = (const int*)d_in[1];
  const int E = in_sizes[1] / 2;
  const int* src = ei;
  const int* dst = ei + E;
  const float* in_w = (const float*)d_in[2];
  const float* in_b = (const float*)d_in[3];
  const float* w1 = (const float*)d_in[4];
  const float* b1 = (const float*)d_in[5];
  const float* ln_g = (const float*)d_in[6];
  const float* ln_b = (const float*)d_in[7];
  const float* w2 = (const float*)d_in[8];
  const float* b2 = (const float*)d_in[9];
  const float* w3 = (const float*)d_in[10];
  const float* b3 = (const float*)d_in[11];
  const float* out_w = (const float*)d_in[12];
  const float* out_b = (const float*)d_in[13];
  float* out = (float*)d_out;

  char* ws = (char*)d_ws;
  size_t off = 0;
  auto alloc = [&](size_t bytes) -> void* {
    void* p = ws + off;
    off += (bytes + 255) & ~(size_t)255;
    return p;
  };
  // ---- layout (~251 MB, ws is 256 MiB) ----
  int* rowptr = (int*)alloc((NN + 1) * 4);
  int* cursor = (int*)alloc((size_t)NN * 4);
  int* cols = (int*)alloc((size_t)E * 4);
  int* sums = (int*)alloc(1024);
  int* sums2 = (int*)alloc(256);
  unsigned short* in_wb_h = (unsigned short*)alloc((size_t)HD * DIN * 2);
  unsigned short* in_wb_l = (unsigned short*)alloc((size_t)HD * DIN * 2);
  unsigned short* w1b = (unsigned short*)alloc(2ul * DMID * DCAT * 2);
  unsigned short* w2b = (unsigned short*)alloc(2ul * DMID * DMID * 2);
  unsigned short* w3b = (unsigned short*)alloc(2ul * HD * DMID * 2);
  unsigned short* out_wb_h = (unsigned short*)alloc((size_t)DOUT * DSUM * 2);
  unsigned short* out_wb_l = (unsigned short*)alloc((size_t)DOUT * DSUM * 2);
  unsigned short* xpart = (unsigned short*)alloc((size_t)NN * DIN * 2);   // 25.6 MB
  unsigned short* h = (unsigned short*)alloc((size_t)NN * HD * 2);        // 51.2 MB
  unsigned char* h8 = (unsigned char*)alloc((size_t)NN * HD);             // 25.6 MB
  unsigned short* hpart = (unsigned short*)alloc((size_t)NN * HD * 2);    // 51.2 MB
  unsigned short* h1c = (unsigned short*)alloc((size_t)CH * DMID * 2);    // 39.3 MB
  unsigned short* h2c = (unsigned short*)alloc((size_t)CH * DMID * 2);    // 39.3 MB
  const size_t need = off;

  if (need > ws_size) {
    sentinel_fill<<<2048, 256, 0, stream>>>(out, (long)NN * DOUT, (float)ws_size);
    return;
  }

  // Aliases (dead-range reuse, safe by stream order):
  //  - x hi/lo split lives in hpart until first agg_h.
  //  - x8 fp8 copy lives in h1c until first GEMM1.
  unsigned short* xb_h = hpart;
  unsigned short* xb_l = hpart + (size_t)NN * DIN;
  unsigned char* x8 = (unsigned char*)h1c;

  hipMemsetAsync(rowptr, 0, (NN + 1) * 4, stream);
  hipMemsetAsync(cursor, 0, (size_t)NN * 4, stream);

  const int eb = (E + 255) / 256;
  const int nscan = NN + 1;
  const int nsb = (nscan + 255) / 256;

  deg_kernel<<<eb, 256, 0, stream>>>(dst, E, rowptr);
  scan_block<<<nsb, 256, 0, stream>>>(rowptr, nscan, sums);
  scan_block<<<1, 256, 0, stream>>>(sums, nsb, sums2);
  scan_add<<<nsb, 256, 0, stream>>>(rowptr, nscan, sums);
  fill_kernel<<<eb, 256, 0, stream>>>(src, dst, E, rowptr, cursor, cols);

  cast_split8_kernel<<<2048, 256, 0, stream>>>(x, xb_h, xb_l, x8, (long)NN * DIN / 4);
  cast_transpose_kernel<true><<<dim3(DIN / 32, HD / 32, 1), 256, 0, stream>>>(in_w, in_wb_h, in_wb_l, DIN, HD);
  cast_transpose_kernel<false><<<dim3(DCAT / 32, DMID / 32, 2), 256, 0, stream>>>(w1, w1b, nullptr, DCAT, DMID);
  cast_transpose_kernel<false><<<dim3(DMID / 32, DMID / 32, 2), 256, 0, stream>>>(w2, w2b, nullptr, DMID, DMID);
  cast_transpose_kernel<false><<<dim3(DMID / 32, HD / 32, 2), 256, 0, stream>>>(w3, w3b, nullptr, DMID, HD);
  cast_transpose_kernel<true><<<dim3(DSUM / 32, DOUT / 32, 1), 256, 0, stream>>>(out_w, out_wb_h, out_wb_l, DSUM, DOUT);

  const int MT = (NN + 127) / 128;  // 391
  const int AGB = NN / 4;           // 12500 blocks, wave-per-node

  // in_proj: h0 = bf16(x@in_w + in_b), + fp8 copy  (A hi/lo, B hi/lo: 3 passes, BK=32)
  gemmx<1, true, true, false, true, 2, 32><<<dim3(MT, HD / 128), 256, 0, stream>>>(
      xb_h, xb_l, DIN, in_wb_h, in_wb_l, DIN, in_b,
      nullptr, h, h8, HD, NN, DIN);

  // xpart = bf16(xb + A@x8)   (iteration-invariant; reads xb/x8 aliases)
  agg_x_kernel<<<AGB, 256, 0, stream>>>(xb_h, x8, rowptr, cols, xpart);

  // out = out_b + h0 @ out_w[0:512]   (B hi/lo: 2 passes, BK=32)
  gemmx<0, false, true, false, false, 2, 32><<<dim3(MT, DOUT / 128), 256, 0, stream>>>(
      h, nullptr, HD, out_wb_h, out_wb_l, DSUM, out_b,
      out, nullptr, nullptr, DOUT, NN, HD);

  for (int i = 0; i < 2; i++) {
    // hpart = bf16(h_i + A@h8_i)  (clobbers xb alias — xb dead by now)
    agg_h_kernel<<<AGB, 256, 0, stream>>>(h, h8, rowptr, cols, hpart);

    // MLP chunked over rows; GEMM3 writes h_{i+1} (+fp8) in place over h
    for (int r0 = 0; r0 < NN; r0 += CH) {
      int Mc = NN - r0 < CH ? NN - r0 : CH;
      int MTc = (Mc + 127) / 128;
      // GEMM1: A split = [xpart | hpart], K=768, dbuf BK=64
      gemm1p<false, false, 64><<<dim3(MTc, DMID / 128), 256, 0, stream>>>(
          xpart + (size_t)r0 * DIN, hpart + (size_t)r0 * HD, DIN, HD, DIN,
          w1b + (size_t)i * DMID * DCAT, DCAT,
          b1 + i * DMID, h1c, nullptr, DMID, Mc, DCAT);
      ln_leaky_kernel<<<Mc, 256, 0, stream>>>(h1c, ln_g + i * DMID, ln_b + i * DMID);
      // GEMM2: fused leaky, dbuf BK=64
      gemm1p<true, false, 64><<<dim3(MTc, DMID / 128), 256, 0, stream>>>(
          h1c, h1c, DMID, DMID, 1 << 30,
          w2b + (size_t)i * DMID * DMID, DMID,
          b2 + i * DMID, h2c, nullptr, DMID, Mc, DMID);
      // GEMM3: writes h_{i+1} bf16 + fp8, dbuf BK=64
      gemm1p<false, true, 64><<<dim3(MTc, HD / 128), 256, 0, stream>>>(
          h2c, h2c, DMID, DMID, 1 << 30,
          w3b + (size_t)i * HD * DMID, DMID,
          b3 + i * HD, h + (size_t)r0 * HD, h8 + (size_t)r0 * HD, HD, Mc, DMID);
    }

    // out += h_{i+1} @ out_w[512*(i+1) : 512*(i+2)]   (B hi/lo: 2 passes, BK=32)
    gemmx<0, false, true, true, false, 2, 32><<<dim3(MT, DOUT / 128), 256, 0, stream>>>(
        h, nullptr, HD,
        out_wb_h + (size_t)(i + 1) * HD, out_wb_l + (size_t)(i + 1) * HD, DSUM,
        nullptr, out, nullptr, nullptr, DOUT, NN, HD);
  }
}

// Round 12
// 1743.666 us; speedup vs baseline: 1.2561x; 1.2561x over previous
//
#include <hip/hip_runtime.h>
#include <hip/hip_bf16.h>

#define NN 50000
#define DIN 256
#define HD 512
#define DCAT 768
#define DMID 1024
#define DSUM 1536
#define DOUT 256
#define CH 19200
#define LN_EPS 1e-5f

typedef __attribute__((ext_vector_type(8))) short short8;
typedef __attribute__((ext_vector_type(4))) float f32x4;
typedef __attribute__((ext_vector_type(2))) float f32x2;

__device__ __forceinline__ unsigned short f2b(float f) {
  unsigned int u = __float_as_uint(f);
  u += 0x7FFF + ((u >> 16) & 1);   // round-to-nearest-even
  return (unsigned short)(u >> 16);
}
__device__ __forceinline__ float b2f(unsigned short s) {
  return __uint_as_float(((unsigned int)s) << 16);
}
__device__ __forceinline__ void splitbf(float v, unsigned short& hi, unsigned short& lo) {
  hi = f2b(v);
  lo = f2b(v - b2f(hi));
}
// fp8 e4m3 encode (hardware, saturating)
__device__ __forceinline__ unsigned char f2e4m3(float v) {
  return (unsigned char)(__builtin_amdgcn_cvt_pk_fp8_f32(v, v, 0, false) & 0xff);
}

// ---------------- diagnostic fill ----------------
__global__ void sentinel_fill(float* __restrict__ out, long n, float v) {
  for (long i = (long)blockIdx.x * blockDim.x + threadIdx.x; i < n;
       i += (long)gridDim.x * blockDim.x)
    out[i] = v;
}

// ---------------- casts / splits ----------------
// x -> bf16 hi/lo + fp8 in one pass
__global__ void cast_split8_kernel(const float* __restrict__ in,
                                   unsigned short* __restrict__ oh,
                                   unsigned short* __restrict__ ol,
                                   unsigned char* __restrict__ o8, long n4) {
  for (long i = (long)blockIdx.x * blockDim.x + threadIdx.x; i < n4;
       i += (long)gridDim.x * blockDim.x) {
    float4 v = ((const float4*)in)[i];
    ushort4 h, l;
    splitbf(v.x, h.x, l.x); splitbf(v.y, h.y, l.y);
    splitbf(v.z, h.z, l.z); splitbf(v.w, h.w, l.w);
    ((ushort4*)oh)[i] = h;
    ((ushort4*)ol)[i] = l;
    unsigned int r = __builtin_amdgcn_cvt_pk_fp8_f32(v.x, v.y, 0, false);
    r = __builtin_amdgcn_cvt_pk_fp8_f32(v.z, v.w, r, true);
    ((unsigned int*)o8)[i] = r;
  }
}

// in: [K][N] f32 -> out hi(/lo): [N][K] bf16  (K,N multiples of 32). blockIdx.z = matrix idx
template <bool SPLIT>
__global__ void cast_transpose_kernel(const float* __restrict__ in,
                                      unsigned short* __restrict__ oh,
                                      unsigned short* __restrict__ ol, int K, int N) {
  const float* src = in + (long)blockIdx.z * K * N;
  unsigned short* dh = oh + (long)blockIdx.z * K * N;
  unsigned short* dl = SPLIT ? ol + (long)blockIdx.z * K * N : nullptr;
  __shared__ unsigned short th[32][33];
  __shared__ unsigned short tl[SPLIT ? 32 : 1][33];
  int bk = blockIdx.x * 32, bn = blockIdx.y * 32;
  int tx = threadIdx.x & 31, ty = threadIdx.x >> 5;
#pragma unroll
  for (int i = ty; i < 32; i += 8) {
    float v = src[(long)(bk + i) * N + bn + tx];
    if (SPLIT) {
      unsigned short h, l;
      splitbf(v, h, l);
      th[i][tx] = h; tl[i][tx] = l;
    } else {
      th[i][tx] = f2b(v);
    }
  }
  __syncthreads();
#pragma unroll
  for (int i = ty; i < 32; i += 8) {
    dh[(long)(bn + i) * K + bk + tx] = th[tx][i];
    if (SPLIT) dl[(long)(bn + i) * K + bk + tx] = tl[tx][i];
  }
}

// ---------------- CSR build ----------------
__global__ void deg_kernel(const int* __restrict__ dst, int E, int* __restrict__ rowptr) {
  int i = blockIdx.x * blockDim.x + threadIdx.x;
  if (i < E) atomicAdd(&rowptr[dst[i] + 1], 1);
}

__global__ void scan_block(int* __restrict__ data, int n, int* __restrict__ sums) {
  __shared__ int tmp[2][256];
  int i = blockIdx.x * 256 + threadIdx.x;
  int v = (i < n) ? data[i] : 0;
  int pp = 0;
  tmp[0][threadIdx.x] = v;
  __syncthreads();
#pragma unroll
  for (int off = 1; off < 256; off <<= 1) {
    int t2 = tmp[pp][threadIdx.x];
    if (threadIdx.x >= off) t2 += tmp[pp][threadIdx.x - off];
    tmp[pp ^ 1][threadIdx.x] = t2;
    pp ^= 1;
    __syncthreads();
  }
  if (i < n) data[i] = tmp[pp][threadIdx.x];
  if (threadIdx.x == 255) sums[blockIdx.x] = tmp[pp][255];
}

__global__ void scan_add(int* __restrict__ data, int n, const int* __restrict__ sums) {
  int i = blockIdx.x * 256 + threadIdx.x;
  if (blockIdx.x > 0 && i < n) data[i] += sums[blockIdx.x - 1];
}

__global__ void fill_kernel(const int* __restrict__ src, const int* __restrict__ dst, int E,
                            const int* __restrict__ rowptr, int* __restrict__ cursor,
                            int* __restrict__ cols) {
  int i = blockIdx.x * blockDim.x + threadIdx.x;
  if (i < E) {
    int r = dst[i];
    int p = rowptr[r] + atomicAdd(&cursor[r], 1);
    cols[p] = src[i];
  }
}

// ---------------- aggregation (wave-per-node; fp8 neighbor gather; round-8 proven) ----------------
// xpart[i,:] = bf16(xb_i + sum_j x8_j)  (own bf16, neighbors fp8 256B/row)
__global__ void agg_x_kernel(const unsigned short* __restrict__ xb,
                             const unsigned char* __restrict__ x8,
                             const int* __restrict__ rowptr,
                             const int* __restrict__ cols,
                             unsigned short* __restrict__ xpart) {
  int node = blockIdx.x * 4 + (threadIdx.x >> 6);
  int lane = threadIdx.x & 63;
  ushort4 own = *((const ushort4*)(xb + (long)node * DIN) + lane);
  float s0 = b2f(own.x), s1 = b2f(own.y), s2 = b2f(own.z), s3 = b2f(own.w);
  int e0 = rowptr[node], e1 = rowptr[node + 1];
  int p = e0;
#define XACC(w)                                                   \
  {                                                               \
    f32x2 t0 = __builtin_amdgcn_cvt_pk_f32_fp8((w), false);       \
    f32x2 t1 = __builtin_amdgcn_cvt_pk_f32_fp8((w), true);        \
    s0 += t0.x; s1 += t0.y; s2 += t1.x; s3 += t1.y;               \
  }
  for (; p + 3 < e1; p += 4) {
    int j0 = cols[p], j1 = cols[p + 1], j2 = cols[p + 2], j3 = cols[p + 3];
    unsigned int a = *((const unsigned int*)(x8 + (long)j0 * DIN) + lane);
    unsigned int b = *((const unsigned int*)(x8 + (long)j1 * DIN) + lane);
    unsigned int c = *((const unsigned int*)(x8 + (long)j2 * DIN) + lane);
    unsigned int d = *((const unsigned int*)(x8 + (long)j3 * DIN) + lane);
    XACC(a); XACC(b); XACC(c); XACC(d);
  }
  for (; p < e1; p++) {
    unsigned int a = *((const unsigned int*)(x8 + (long)cols[p] * DIN) + lane);
    XACC(a);
  }
#undef XACC
  ushort4 o;
  o.x = f2b(s0); o.y = f2b(s1); o.z = f2b(s2); o.w = f2b(s3);
  *((ushort4*)(xpart + (long)node * DIN) + lane) = o;
}

// hpart[i,:] = bf16(h_i + sum_j h8_j)  (own bf16 1KB, neighbors fp8 512B/row)
__global__ void agg_h_kernel(const unsigned short* __restrict__ h,
                             const unsigned char* __restrict__ h8,
                             const int* __restrict__ rowptr, const int* __restrict__ cols,
                             unsigned short* __restrict__ hpart) {
  int node = blockIdx.x * 4 + (threadIdx.x >> 6);
  int lane = threadIdx.x & 63;
  short8 own = *((const short8*)(h + (long)node * HD) + lane);
  float s[8];
#pragma unroll
  for (int q = 0; q < 8; q++) s[q] = b2f((unsigned short)own[q]);
  int e0 = rowptr[node], e1 = rowptr[node + 1];
  int p = e0;
#define HACC(w)                                                   \
  {                                                               \
    f32x2 t0 = __builtin_amdgcn_cvt_pk_f32_fp8((w).x, false);     \
    f32x2 t1 = __builtin_amdgcn_cvt_pk_f32_fp8((w).x, true);      \
    f32x2 t2 = __builtin_amdgcn_cvt_pk_f32_fp8((w).y, false);     \
    f32x2 t3 = __builtin_amdgcn_cvt_pk_f32_fp8((w).y, true);      \
    s[0] += t0.x; s[1] += t0.y; s[2] += t1.x; s[3] += t1.y;       \
    s[4] += t2.x; s[5] += t2.y; s[6] += t3.x; s[7] += t3.y;       \
  }
  for (; p + 3 < e1; p += 4) {
    int j0 = cols[p], j1 = cols[p + 1], j2 = cols[p + 2], j3 = cols[p + 3];
    uint2 a = *((const uint2*)(h8 + (long)j0 * HD) + lane);
    uint2 b = *((const uint2*)(h8 + (long)j1 * HD) + lane);
    uint2 c = *((const uint2*)(h8 + (long)j2 * HD) + lane);
    uint2 d = *((const uint2*)(h8 + (long)j3 * HD) + lane);
    HACC(a); HACC(b); HACC(c); HACC(d);
  }
  for (; p < e1; p++) {
    uint2 a = *((const uint2*)(h8 + (long)cols[p] * HD) + lane);
    HACC(a);
  }
#undef HACC
  short8 o;
#pragma unroll
  for (int q = 0; q < 8; q++) o[q] = (short)f2b(s[q]);
  *((short8*)(hpart + (long)node * HD) + lane) = o;
}

// ---------------- LayerNorm + leaky on bf16 rows of width 1024 (in place) ----------------
__global__ void ln_leaky_kernel(unsigned short* __restrict__ arr,
                                const float* __restrict__ gamma,
                                const float* __restrict__ beta) {
  int row = blockIdx.x, t = threadIdx.x;
  unsigned short* p = arr + (long)row * DMID;
  ushort4 u = ((const ushort4*)p)[t];
  float v0 = b2f(u.x), v1 = b2f(u.y), v2 = b2f(u.z), v3 = b2f(u.w);
  float s = v0 + v1 + v2 + v3;
  float sq = v0 * v0 + v1 * v1 + v2 * v2 + v3 * v3;
#pragma unroll
  for (int off = 32; off >= 1; off >>= 1) {
    s += __shfl_down(s, off, 64);
    sq += __shfl_down(sq, off, 64);
  }
  __shared__ float red[8];
  int w = t >> 6, lane = t & 63;
  if (lane == 0) { red[w] = s; red[4 + w] = sq; }
  __syncthreads();
  s = red[0] + red[1] + red[2] + red[3];
  sq = red[4] + red[5] + red[6] + red[7];
  float mean = s * (1.f / DMID);
  float var = sq * (1.f / DMID) - mean * mean;
  float rstd = rsqrtf(var + LN_EPS);
  float4 gv = ((const float4*)gamma)[t];
  float4 bv = ((const float4*)beta)[t];
  float o0 = (v0 - mean) * rstd * gv.x + bv.x;
  float o1 = (v1 - mean) * rstd * gv.y + bv.y;
  float o2 = (v2 - mean) * rstd * gv.z + bv.z;
  float o3 = (v3 - mean) * rstd * gv.w + bv.w;
  o0 = o0 > 0.f ? o0 : 0.1f * o0;
  o1 = o1 > 0.f ? o1 : 0.1f * o1;
  o2 = o2 > 0.f ? o2 : 0.1f * o2;
  o3 = o3 > 0.f ? o3 : 0.1f * o3;
  ushort4 ou;
  ou.x = f2b(o0); ou.y = f2b(o1); ou.z = f2b(o2); ou.w = f2b(o3);
  ((ushort4*)p)[t] = ou;
}

#define GLD16(src, dst)                                                          \
  __builtin_amdgcn_global_load_lds(                                              \
      (const __attribute__((address_space(1))) void*)(src),                      \
      (__attribute__((address_space(3))) void*)(dst), 16, 0, 0)

// ---------------- 1-pass conv GEMM: round-10 K-loop + LDS-repacked coalesced epilogue ----------------
// C[M,N] = A[M,K] * Bt[N,K]^T + bias. 128x128 tile, BK=64, 4 waves (2x2), OCC=3.
// Epilogue: acc -> LDS C-tile [128][136] (padded) -> 16B-coalesced global stores.
template <bool ACT, bool W8, int BK>
__launch_bounds__(256, 3)
__global__ void gemm1p(const unsigned short* __restrict__ Ah,
                       const unsigned short* __restrict__ A2h,
                       int lda, int lda2, int ksplit,
                       const unsigned short* __restrict__ Bh,
                       int ldb, const float* __restrict__ bias,
                       unsigned short* __restrict__ Chi,
                       unsigned char* __restrict__ C8,
                       int ldc, int M, int K) {
  constexpr int CT_LD = 136;
  constexpr int STAGE_B = 2 * 128 * BK * 2;
  constexpr int CT_B = 128 * CT_LD * 2;
  constexpr int C8_B = W8 ? 128 * CT_LD : 0;
  constexpr int SMEM_B = (STAGE_B > CT_B + C8_B) ? STAGE_B : (CT_B + C8_B);
  __shared__ __align__(16) unsigned char smem[SMEM_B];
  unsigned short* Ash = (unsigned short*)smem;
  unsigned short* Bsh = Ash + 128 * BK;
  const int t = threadIdx.x;
  const int bm = blockIdx.x, bn = blockIdx.y;
  const int l = t & 63;
  const int w = t >> 6;
  const int wm = w >> 1, wn = w & 1;
  const int lrow = l & 15, lk = (l >> 4) * 8;

  f32x4 acc[4][4] = {};

  const int arow0 = bm * 128;
  const int brow0 = bn * 128;

  for (int k0 = 0; k0 < K; k0 += BK) {
    const bool first = k0 < ksplit;
    const unsigned short* Abase = first ? Ah : A2h;
    const int acol = first ? k0 : (k0 - ksplit);
    const int alda = first ? lda : lda2;
    __syncthreads();
#pragma unroll
    for (int it = 0; it < BK / 16; it++) {
      int c = t + it * 256;
      int row = c / (BK / 8);
      int sk = (c % (BK / 8)) * 8;
      int ar = arow0 + row;
      if (ar >= M) ar = M - 1;
      int ldst = row * BK + sk;     // lane*16B from wave-uniform base (layout law m104)
      GLD16(Abase + (long)ar * alda + acol + sk, Ash + ldst);
      GLD16(Bh + (long)(brow0 + row) * ldb + k0 + sk, Bsh + ldst);
    }
    __syncthreads();
#pragma unroll
    for (int kk = 0; kk < BK / 32; kk++) {
      short8 ah[4], bh4[4];
#pragma unroll
      for (int m = 0; m < 4; m++)
        ah[m] = *(const short8*)(Ash + (wm * 64 + m * 16 + lrow) * BK + kk * 32 + lk);
#pragma unroll
      for (int n = 0; n < 4; n++)
        bh4[n] = *(const short8*)(Bsh + (wn * 64 + n * 16 + lrow) * BK + kk * 32 + lk);
#pragma unroll
      for (int m = 0; m < 4; m++)
#pragma unroll
        for (int n = 0; n < 4; n++)
          acc[m][n] = __builtin_amdgcn_mfma_f32_16x16x32_bf16(ah[m], bh4[n], acc[m][n], 0, 0, 0);
    }
  }

  // ---- epilogue: repack through LDS, then coalesced stores ----
  __syncthreads();                         // all staging reads done before overlay
  unsigned short* Ct = (unsigned short*)smem;
  unsigned char* C8t = smem + CT_B;
  const int orl = wm * 64 + (l >> 4) * 4;
  const int ocl = wn * 64 + lrow;
#pragma unroll
  for (int n = 0; n < 4; n++) {
    float bv = bias[bn * 128 + ocl + n * 16];
#pragma unroll
    for (int m = 0; m < 4; m++) {
#pragma unroll
      for (int ri = 0; ri < 4; ri++) {
        float v = acc[m][n][ri] + bv;
        if constexpr (ACT) v = v > 0.f ? v : 0.1f * v;
        int rr = orl + m * 16 + ri, cc = ocl + n * 16;
        Ct[rr * CT_LD + cc] = f2b(v);
        if constexpr (W8) C8t[rr * CT_LD + cc] = f2e4m3(v);  // fp8 from original f32
      }
    }
  }
  __syncthreads();
  const long row0 = bm * 128;
  const long col0 = bn * 128;
#pragma unroll
  for (int p = 0; p < 8; p++) {
    int idx = t + p * 256;
    int r = idx >> 4, cb = (idx & 15) * 8;
    long gr = row0 + r;
    if (gr < M)
      *(short8*)(Chi + gr * ldc + col0 + cb) = *(const short8*)(Ct + r * CT_LD + cb);
  }
  if constexpr (W8) {
#pragma unroll
    for (int p = 0; p < 8; p++) {
      int idx = t + p * 256;
      int r = idx >> 4, cb = (idx & 15) * 8;
      long gr = row0 + r;
      if (gr < M)
        *(uint2*)(C8 + gr * ldc + col0 + cb) = *(const uint2*)(C8t + r * CT_LD + cb);
    }
  }
}

// ---------------- multi-pass MFMA GEMM (in_proj / out): round-10 structure ----------------
template <int WMODE, bool AL, bool BL, bool ACC, bool W8, int OCC, int BK>
__launch_bounds__(256, OCC)
__global__ void gemmx(const unsigned short* __restrict__ Ah,
                      const unsigned short* __restrict__ Al,
                      int lda,
                      const unsigned short* __restrict__ Bh,
                      const unsigned short* __restrict__ Bl,
                      int ldb, const float* __restrict__ bias,
                      float* __restrict__ Cf,
                      unsigned short* __restrict__ Chi,
                      unsigned char* __restrict__ C8,
                      int ldc, int M, int K) {
  __shared__ __align__(16) unsigned short Ash[128 * BK];
  __shared__ __align__(16) unsigned short Asl[AL ? 128 * BK : 16];
  __shared__ __align__(16) unsigned short Bsh[128 * BK];
  __shared__ __align__(16) unsigned short Bsl[BL ? 128 * BK : 16];
  const int t = threadIdx.x;
  const int bm = blockIdx.x, bn = blockIdx.y;
  const int l = t & 63;
  const int w = t >> 6;
  const int wm = w >> 1, wn = w & 1;
  const int lrow = l & 15, lk = (l >> 4) * 8;

  f32x4 acc[4][4] = {};

  const int arow0 = bm * 128;
  const int brow0 = bn * 128;

  for (int k0 = 0; k0 < K; k0 += BK) {
    __syncthreads();
#pragma unroll
    for (int it = 0; it < BK / 16; it++) {
      int c = t + it * 256;
      int row = c / (BK / 8);
      int sk = (c % (BK / 8)) * 8;
      int ar = arow0 + row;
      if (ar >= M) ar = M - 1;
      long boff = (long)(brow0 + row) * ldb + k0 + sk;
      int ldst = row * BK + sk;
      GLD16(Ah + (long)ar * lda + k0 + sk, Ash + ldst);
      if (AL) GLD16(Al + (long)ar * lda + k0 + sk, Asl + ldst);
      GLD16(Bh + boff, Bsh + ldst);
      if (BL) GLD16(Bl + boff, Bsl + ldst);
    }
    __syncthreads();
#pragma unroll
    for (int kk = 0; kk < BK / 32; kk++) {
      short8 ah[4], al4[4], bh[4], bl4[4];
#pragma unroll
      for (int m = 0; m < 4; m++) {
        int ro = (wm * 64 + m * 16 + lrow) * BK + kk * 32 + lk;
        ah[m] = *(const short8*)(Ash + ro);
        if (AL) al4[m] = *(const short8*)(Asl + ro);
      }
#pragma unroll
      for (int n = 0; n < 4; n++) {
        int ro = (wn * 64 + n * 16 + lrow) * BK + kk * 32 + lk;
        bh[n] = *(const short8*)(Bsh + ro);
        if (BL) bl4[n] = *(const short8*)(Bsl + ro);
      }
#pragma unroll
      for (int m = 0; m < 4; m++)
#pragma unroll
        for (int n = 0; n < 4; n++) {
          acc[m][n] = __builtin_amdgcn_mfma_f32_16x16x32_bf16(ah[m], bh[n], acc[m][n], 0, 0, 0);
          if (BL)
            acc[m][n] = __builtin_amdgcn_mfma_f32_16x16x32_bf16(ah[m], bl4[n], acc[m][n], 0, 0, 0);
          if (AL)
            acc[m][n] = __builtin_amdgcn_mfma_f32_16x16x32_bf16(al4[m], bh[n], acc[m][n], 0, 0, 0);
        }
    }
  }

  const int orow0 = bm * 128 + wm * 64 + (l >> 4) * 4;
  const int ocol0 = bn * 128 + wn * 64 + lrow;
#pragma unroll
  for (int n = 0; n < 4; n++) {
    int gc = ocol0 + n * 16;
    float bv;
    if constexpr (ACC) bv = 0.f; else bv = bias[gc];
#pragma unroll
    for (int m = 0; m < 4; m++) {
#pragma unroll
      for (int ri = 0; ri < 4; ri++) {
        int gr = orow0 + m * 16 + ri;
        if (gr < M) {
          float v = acc[m][n][ri] + bv;
          if constexpr (ACC) v += Cf[(long)gr * ldc + gc];
          if constexpr (WMODE == 0) {
            Cf[(long)gr * ldc + gc] = v;
          } else {
            Chi[(long)gr * ldc + gc] = f2b(v);
            if constexpr (W8) C8[(long)gr * ldc + gc] = f2e4m3(v);
          }
        }
      }
    }
  }
}

// ---------------- host ----------------
extern "C" void kernel_launch(void* const* d_in, const int* in_sizes, int n_in,
                              void* d_out, int out_size, void* d_ws, size_t ws_size,
                              hipStream_t stream) {
  const float* x = (const float*)d_in[0];
  const int* ei = (const int*)d_in[1];
  const int E = in_sizes[1] / 2;
  const int* src = ei;
  const int* dst = ei + E;
  const float* in_w = (const float*)d_in[2];
  const float* in_b = (const float*)d_in[3];
  const float* w1 = (const float*)d_in[4];
  const float* b1 = (const float*)d_in[5];
  const float* ln_g = (const float*)d_in[6];
  const float* ln_b = (const float*)d_in[7];
  const float* w2 = (const float*)d_in[8];
  const float* b2 = (const float*)d_in[9];
  const float* w3 = (const float*)d_in[10];
  const float* b3 = (const float*)d_in[11];
  const float* out_w = (const float*)d_in[12];
  const float* out_b = (const float*)d_in[13];
  float* out = (float*)d_out;

  char* ws = (char*)d_ws;
  size_t off = 0;
  auto alloc = [&](size_t bytes) -> void* {
    void* p = ws + off;
    off += (bytes + 255) & ~(size_t)255;
    return p;
  };
  // ---- layout (~251 MB, ws is 256 MiB) ----
  int* rowptr = (int*)alloc((NN + 1) * 4);
  int* cursor = (int*)alloc((size_t)NN * 4);
  int* cols = (int*)alloc((size_t)E * 4);
  int* sums = (int*)alloc(1024);
  int* sums2 = (int*)alloc(256);
  unsigned short* in_wb_h = (unsigned short*)alloc((size_t)HD * DIN * 2);
  unsigned short* in_wb_l = (unsigned short*)alloc((size_t)HD * DIN * 2);
  unsigned short* w1b = (unsigned short*)alloc(2ul * DMID * DCAT * 2);
  unsigned short* w2b = (unsigned short*)alloc(2ul * DMID * DMID * 2);
  unsigned short* w3b = (unsigned short*)alloc(2ul * HD * DMID * 2);
  unsigned short* out_wb_h = (unsigned short*)alloc((size_t)DOUT * DSUM * 2);
  unsigned short* out_wb_l = (unsigned short*)alloc((size_t)DOUT * DSUM * 2);
  unsigned short* xpart = (unsigned short*)alloc((size_t)NN * DIN * 2);   // 25.6 MB
  unsigned short* h = (unsigned short*)alloc((size_t)NN * HD * 2);        // 51.2 MB
  unsigned char* h8 = (unsigned char*)alloc((size_t)NN * HD);             // 25.6 MB
  unsigned short* hpart = (unsigned short*)alloc((size_t)NN * HD * 2);    // 51.2 MB
  unsigned short* h1c = (unsigned short*)alloc((size_t)CH * DMID * 2);    // 39.3 MB
  unsigned short* h2c = (unsigned short*)alloc((size_t)CH * DMID * 2);    // 39.3 MB
  const size_t need = off;

  if (need > ws_size) {
    sentinel_fill<<<2048, 256, 0, stream>>>(out, (long)NN * DOUT, (float)ws_size);
    return;
  }

  // Aliases (dead-range reuse, safe by stream order):
  //  - x hi/lo split lives in hpart until first agg_h.
  //  - x8 fp8 copy lives in h1c until first GEMM1.
  unsigned short* xb_h = hpart;
  unsigned short* xb_l = hpart + (size_t)NN * DIN;
  unsigned char* x8 = (unsigned char*)h1c;

  hipMemsetAsync(rowptr, 0, (NN + 1) * 4, stream);
  hipMemsetAsync(cursor, 0, (size_t)NN * 4, stream);

  const int eb = (E + 255) / 256;
  const int nscan = NN + 1;
  const int nsb = (nscan + 255) / 256;

  deg_kernel<<<eb, 256, 0, stream>>>(dst, E, rowptr);
  scan_block<<<nsb, 256, 0, stream>>>(rowptr, nscan, sums);
  scan_block<<<1, 256, 0, stream>>>(sums, nsb, sums2);
  scan_add<<<nsb, 256, 0, stream>>>(rowptr, nscan, sums);
  fill_kernel<<<eb, 256, 0, stream>>>(src, dst, E, rowptr, cursor, cols);

  cast_split8_kernel<<<2048, 256, 0, stream>>>(x, xb_h, xb_l, x8, (long)NN * DIN / 4);
  cast_transpose_kernel<true><<<dim3(DIN / 32, HD / 32, 1), 256, 0, stream>>>(in_w, in_wb_h, in_wb_l, DIN, HD);
  cast_transpose_kernel<false><<<dim3(DCAT / 32, DMID / 32, 2), 256, 0, stream>>>(w1, w1b, nullptr, DCAT, DMID);
  cast_transpose_kernel<false><<<dim3(DMID / 32, DMID / 32, 2), 256, 0, stream>>>(w2, w2b, nullptr, DMID, DMID);
  cast_transpose_kernel<false><<<dim3(DMID / 32, HD / 32, 2), 256, 0, stream>>>(w3, w3b, nullptr, DMID, HD);
  cast_transpose_kernel<true><<<dim3(DSUM / 32, DOUT / 32, 1), 256, 0, stream>>>(out_w, out_wb_h, out_wb_l, DSUM, DOUT);

  const int MT = (NN + 127) / 128;  // 391
  const int AGB = NN / 4;           // 12500 blocks, wave-per-node

  // in_proj: h0 = bf16(x@in_w + in_b), + fp8 copy  (A hi/lo, B hi/lo: 3 passes, BK=32)
  gemmx<1, true, true, false, true, 2, 32><<<dim3(MT, HD / 128), 256, 0, stream>>>(
      xb_h, xb_l, DIN, in_wb_h, in_wb_l, DIN, in_b,
      nullptr, h, h8, HD, NN, DIN);

  // xpart = bf16(xb + A@x8)   (iteration-invariant; reads xb/x8 aliases)
  agg_x_kernel<<<AGB, 256, 0, stream>>>(xb_h, x8, rowptr, cols, xpart);

  // out = out_b + h0 @ out_w[0:512]   (B hi/lo: 2 passes, BK=32)
  gemmx<0, false, true, false, false, 2, 32><<<dim3(MT, DOUT / 128), 256, 0, stream>>>(
      h, nullptr, HD, out_wb_h, out_wb_l, DSUM, out_b,
      out, nullptr, nullptr, DOUT, NN, HD);

  for (int i = 0; i < 2; i++) {
    // hpart = bf16(h_i + A@h8_i)  (clobbers xb alias — xb dead by now)
    agg_h_kernel<<<AGB, 256, 0, stream>>>(h, h8, rowptr, cols, hpart);

    // MLP chunked over rows; GEMM3 writes h_{i+1} (+fp8) in place over h
    for (int r0 = 0; r0 < NN; r0 += CH) {
      int Mc = NN - r0 < CH ? NN - r0 : CH;
      int MTc = (Mc + 127) / 128;
      // GEMM1: A split = [xpart | hpart], K=768, BK=64, repack epilogue
      gemm1p<false, false, 64><<<dim3(MTc, DMID / 128), 256, 0, stream>>>(
          xpart + (size_t)r0 * DIN, hpart + (size_t)r0 * HD, DIN, HD, DIN,
          w1b + (size_t)i * DMID * DCAT, DCAT,
          b1 + i * DMID, h1c, nullptr, DMID, Mc, DCAT);
      ln_leaky_kernel<<<Mc, 256, 0, stream>>>(h1c, ln_g + i * DMID, ln_b + i * DMID);
      // GEMM2: fused leaky, BK=64, repack epilogue
      gemm1p<true, false, 64><<<dim3(MTc, DMID / 128), 256, 0, stream>>>(
          h1c, h1c, DMID, DMID, 1 << 30,
          w2b + (size_t)i * DMID * DMID, DMID,
          b2 + i * DMID, h2c, nullptr, DMID, Mc, DMID);
      // GEMM3: writes h_{i+1} bf16 + fp8, BK=64, repack epilogue
      gemm1p<false, true, 64><<<dim3(MTc, HD / 128), 256, 0, stream>>>(
          h2c, h2c, DMID, DMID, 1 << 30,
          w3b + (size_t)i * HD * DMID, DMID,
          b3 + i * HD, h + (size_t)r0 * HD, h8 + (size_t)r0 * HD, HD, Mc, DMID);
    }

    // out += h_{i+1} @ out_w[512*(i+1) : 512*(i+2)]   (B hi/lo: 2 passes, BK=32)
    gemmx<0, false, true, true, false, 2, 32><<<dim3(MT, DOUT / 128), 256, 0, stream>>>(
        h, nullptr, HD,
        out_wb_h + (size_t)(i + 1) * HD, out_wb_l + (size_t)(i + 1) * HD, DSUM,
        nullptr, out, nullptr, nullptr, DOUT, NN, HD);
  }
}

// Round 13
// 1717.429 us; speedup vs baseline: 1.2753x; 1.0153x over previous
//
#include <hip/hip_runtime.h>
#include <hip/hip_bf16.h>

#define NN 50000
#define DIN 256
#define HD 512
#define DCAT 768
#define DMID 1024
#define DSUM 1536
#define DOUT 256
#define CH 19200
#define LN_EPS 1e-5f

typedef __attribute__((ext_vector_type(8))) short short8;
typedef __attribute__((ext_vector_type(4))) float f32x4;
typedef __attribute__((ext_vector_type(2))) float f32x2;

__device__ __forceinline__ unsigned short f2b(float f) {
  unsigned int u = __float_as_uint(f);
  u += 0x7FFF + ((u >> 16) & 1);   // round-to-nearest-even
  return (unsigned short)(u >> 16);
}
__device__ __forceinline__ float b2f(unsigned short s) {
  return __uint_as_float(((unsigned int)s) << 16);
}
__device__ __forceinline__ void splitbf(float v, unsigned short& hi, unsigned short& lo) {
  hi = f2b(v);
  lo = f2b(v - b2f(hi));
}
// fp8 e4m3 encode (hardware, saturating)
__device__ __forceinline__ unsigned char f2e4m3(float v) {
  return (unsigned char)(__builtin_amdgcn_cvt_pk_fp8_f32(v, v, 0, false) & 0xff);
}

// ---------------- diagnostic fill ----------------
__global__ void sentinel_fill(float* __restrict__ out, long n, float v) {
  for (long i = (long)blockIdx.x * blockDim.x + threadIdx.x; i < n;
       i += (long)gridDim.x * blockDim.x)
    out[i] = v;
}

// ---------------- casts / splits ----------------
// x -> bf16 hi/lo + fp8 in one pass
__global__ void cast_split8_kernel(const float* __restrict__ in,
                                   unsigned short* __restrict__ oh,
                                   unsigned short* __restrict__ ol,
                                   unsigned char* __restrict__ o8, long n4) {
  for (long i = (long)blockIdx.x * blockDim.x + threadIdx.x; i < n4;
       i += (long)gridDim.x * blockDim.x) {
    float4 v = ((const float4*)in)[i];
    ushort4 h, l;
    splitbf(v.x, h.x, l.x); splitbf(v.y, h.y, l.y);
    splitbf(v.z, h.z, l.z); splitbf(v.w, h.w, l.w);
    ((ushort4*)oh)[i] = h;
    ((ushort4*)ol)[i] = l;
    unsigned int r = __builtin_amdgcn_cvt_pk_fp8_f32(v.x, v.y, 0, false);
    r = __builtin_amdgcn_cvt_pk_fp8_f32(v.z, v.w, r, true);
    ((unsigned int*)o8)[i] = r;
  }
}

// in: [K][N] f32 -> out hi(/lo): [N][K] bf16  (K,N multiples of 32). blockIdx.z = matrix idx
template <bool SPLIT>
__global__ void cast_transpose_kernel(const float* __restrict__ in,
                                      unsigned short* __restrict__ oh,
                                      unsigned short* __restrict__ ol, int K, int N) {
  const float* src = in + (long)blockIdx.z * K * N;
  unsigned short* dh = oh + (long)blockIdx.z * K * N;
  unsigned short* dl = SPLIT ? ol + (long)blockIdx.z * K * N : nullptr;
  __shared__ unsigned short th[32][33];
  __shared__ unsigned short tl[SPLIT ? 32 : 1][33];
  int bk = blockIdx.x * 32, bn = blockIdx.y * 32;
  int tx = threadIdx.x & 31, ty = threadIdx.x >> 5;
#pragma unroll
  for (int i = ty; i < 32; i += 8) {
    float v = src[(long)(bk + i) * N + bn + tx];
    if (SPLIT) {
      unsigned short h, l;
      splitbf(v, h, l);
      th[i][tx] = h; tl[i][tx] = l;
    } else {
      th[i][tx] = f2b(v);
    }
  }
  __syncthreads();
#pragma unroll
  for (int i = ty; i < 32; i += 8) {
    dh[(long)(bn + i) * K + bk + tx] = th[tx][i];
    if (SPLIT) dl[(long)(bn + i) * K + bk + tx] = tl[tx][i];
  }
}

// ---------------- CSR build ----------------
__global__ void deg_kernel(const int* __restrict__ dst, int E, int* __restrict__ rowptr) {
  int i = blockIdx.x * blockDim.x + threadIdx.x;
  if (i < E) atomicAdd(&rowptr[dst[i] + 1], 1);
}

__global__ void scan_block(int* __restrict__ data, int n, int* __restrict__ sums) {
  __shared__ int tmp[2][256];
  int i = blockIdx.x * 256 + threadIdx.x;
  int v = (i < n) ? data[i] : 0;
  int pp = 0;
  tmp[0][threadIdx.x] = v;
  __syncthreads();
#pragma unroll
  for (int off = 1; off < 256; off <<= 1) {
    int t2 = tmp[pp][threadIdx.x];
    if (threadIdx.x >= off) t2 += tmp[pp][threadIdx.x - off];
    tmp[pp ^ 1][threadIdx.x] = t2;
    pp ^= 1;
    __syncthreads();
  }
  if (i < n) data[i] = tmp[pp][threadIdx.x];
  if (threadIdx.x == 255) sums[blockIdx.x] = tmp[pp][255];
}

__global__ void scan_add(int* __restrict__ data, int n, const int* __restrict__ sums) {
  int i = blockIdx.x * 256 + threadIdx.x;
  if (blockIdx.x > 0 && i < n) data[i] += sums[blockIdx.x - 1];
}

__global__ void fill_kernel(const int* __restrict__ src, const int* __restrict__ dst, int E,
                            const int* __restrict__ rowptr, int* __restrict__ cursor,
                            int* __restrict__ cols) {
  int i = blockIdx.x * blockDim.x + threadIdx.x;
  if (i < E) {
    int r = dst[i];
    int p = rowptr[r] + atomicAdd(&cursor[r], 1);
    cols[p] = src[i];
  }
}

// ---------------- aggregation (wave-per-node; fp8 neighbor gather; round-8 proven) ----------------
// xpart[i,:] = bf16(xb_i + sum_j x8_j)  (own bf16, neighbors fp8 256B/row)
__global__ void agg_x_kernel(const unsigned short* __restrict__ xb,
                             const unsigned char* __restrict__ x8,
                             const int* __restrict__ rowptr,
                             const int* __restrict__ cols,
                             unsigned short* __restrict__ xpart) {
  int node = blockIdx.x * 4 + (threadIdx.x >> 6);
  int lane = threadIdx.x & 63;
  ushort4 own = *((const ushort4*)(xb + (long)node * DIN) + lane);
  float s0 = b2f(own.x), s1 = b2f(own.y), s2 = b2f(own.z), s3 = b2f(own.w);
  int e0 = rowptr[node], e1 = rowptr[node + 1];
  int p = e0;
#define XACC(w)                                                   \
  {                                                               \
    f32x2 t0 = __builtin_amdgcn_cvt_pk_f32_fp8((w), false);       \
    f32x2 t1 = __builtin_amdgcn_cvt_pk_f32_fp8((w), true);        \
    s0 += t0.x; s1 += t0.y; s2 += t1.x; s3 += t1.y;               \
  }
  for (; p + 3 < e1; p += 4) {
    int j0 = cols[p], j1 = cols[p + 1], j2 = cols[p + 2], j3 = cols[p + 3];
    unsigned int a = *((const unsigned int*)(x8 + (long)j0 * DIN) + lane);
    unsigned int b = *((const unsigned int*)(x8 + (long)j1 * DIN) + lane);
    unsigned int c = *((const unsigned int*)(x8 + (long)j2 * DIN) + lane);
    unsigned int d = *((const unsigned int*)(x8 + (long)j3 * DIN) + lane);
    XACC(a); XACC(b); XACC(c); XACC(d);
  }
  for (; p < e1; p++) {
    unsigned int a = *((const unsigned int*)(x8 + (long)cols[p] * DIN) + lane);
    XACC(a);
  }
#undef XACC
  ushort4 o;
  o.x = f2b(s0); o.y = f2b(s1); o.z = f2b(s2); o.w = f2b(s3);
  *((ushort4*)(xpart + (long)node * DIN) + lane) = o;
}

// hpart[i,:] = bf16(h_i + sum_j h8_j)  (own bf16 1KB, neighbors fp8 512B/row)
__global__ void agg_h_kernel(const unsigned short* __restrict__ h,
                             const unsigned char* __restrict__ h8,
                             const int* __restrict__ rowptr, const int* __restrict__ cols,
                             unsigned short* __restrict__ hpart) {
  int node = blockIdx.x * 4 + (threadIdx.x >> 6);
  int lane = threadIdx.x & 63;
  short8 own = *((const short8*)(h + (long)node * HD) + lane);
  float s[8];
#pragma unroll
  for (int q = 0; q < 8; q++) s[q] = b2f((unsigned short)own[q]);
  int e0 = rowptr[node], e1 = rowptr[node + 1];
  int p = e0;
#define HACC(w)                                                   \
  {                                                               \
    f32x2 t0 = __builtin_amdgcn_cvt_pk_f32_fp8((w).x, false);     \
    f32x2 t1 = __builtin_amdgcn_cvt_pk_f32_fp8((w).x, true);      \
    f32x2 t2 = __builtin_amdgcn_cvt_pk_f32_fp8((w).y, false);     \
    f32x2 t3 = __builtin_amdgcn_cvt_pk_f32_fp8((w).y, true);      \
    s[0] += t0.x; s[1] += t0.y; s[2] += t1.x; s[3] += t1.y;       \
    s[4] += t2.x; s[5] += t2.y; s[6] += t3.x; s[7] += t3.y;       \
  }
  for (; p + 3 < e1; p += 4) {
    int j0 = cols[p], j1 = cols[p + 1], j2 = cols[p + 2], j3 = cols[p + 3];
    uint2 a = *((const uint2*)(h8 + (long)j0 * HD) + lane);
    uint2 b = *((const uint2*)(h8 + (long)j1 * HD) + lane);
    uint2 c = *((const uint2*)(h8 + (long)j2 * HD) + lane);
    uint2 d = *((const uint2*)(h8 + (long)j3 * HD) + lane);
    HACC(a); HACC(b); HACC(c); HACC(d);
  }
  for (; p < e1; p++) {
    uint2 a = *((const uint2*)(h8 + (long)cols[p] * HD) + lane);
    HACC(a);
  }
#undef HACC
  short8 o;
#pragma unroll
  for (int q = 0; q < 8; q++) o[q] = (short)f2b(s[q]);
  *((short8*)(hpart + (long)node * HD) + lane) = o;
}

// ---------------- LayerNorm + leaky on bf16 rows of width 1024 (in place) ----------------
__global__ void ln_leaky_kernel(unsigned short* __restrict__ arr,
                                const float* __restrict__ gamma,
                                const float* __restrict__ beta) {
  int row = blockIdx.x, t = threadIdx.x;
  unsigned short* p = arr + (long)row * DMID;
  ushort4 u = ((const ushort4*)p)[t];
  float v0 = b2f(u.x), v1 = b2f(u.y), v2 = b2f(u.z), v3 = b2f(u.w);
  float s = v0 + v1 + v2 + v3;
  float sq = v0 * v0 + v1 * v1 + v2 * v2 + v3 * v3;
#pragma unroll
  for (int off = 32; off >= 1; off >>= 1) {
    s += __shfl_down(s, off, 64);
    sq += __shfl_down(sq, off, 64);
  }
  __shared__ float red[8];
  int w = t >> 6, lane = t & 63;
  if (lane == 0) { red[w] = s; red[4 + w] = sq; }
  __syncthreads();
  s = red[0] + red[1] + red[2] + red[3];
  sq = red[4] + red[5] + red[6] + red[7];
  float mean = s * (1.f / DMID);
  float var = sq * (1.f / DMID) - mean * mean;
  float rstd = rsqrtf(var + LN_EPS);
  float4 gv = ((const float4*)gamma)[t];
  float4 bv = ((const float4*)beta)[t];
  float o0 = (v0 - mean) * rstd * gv.x + bv.x;
  float o1 = (v1 - mean) * rstd * gv.y + bv.y;
  float o2 = (v2 - mean) * rstd * gv.z + bv.z;
  float o3 = (v3 - mean) * rstd * gv.w + bv.w;
  o0 = o0 > 0.f ? o0 : 0.1f * o0;
  o1 = o1 > 0.f ? o1 : 0.1f * o1;
  o2 = o2 > 0.f ? o2 : 0.1f * o2;
  o3 = o3 > 0.f ? o3 : 0.1f * o3;
  ushort4 ou;
  ou.x = f2b(o0); ou.y = f2b(o1); ou.z = f2b(o2); ou.w = f2b(o3);
  ((ushort4*)p)[t] = ou;
}

#define GLD16(src, dst)                                                          \
  __builtin_amdgcn_global_load_lds(                                              \
      (const __attribute__((address_space(1))) void*)(src),                      \
      (__attribute__((address_space(3))) void*)(dst), 16, 0, 0)

// ---------------- 1-pass conv GEMM: XCD-grouped 1-D grid + repack epilogue ----------------
// Launch: MT8*NT blocks (MT8 = ceil(MT/8)*8). Remap lin -> (bm,bn) so that all NT
// blocks sharing an A row-panel land on the SAME XCD (round-robin lin%8 assumption):
// A-panel fetched once per panel instead of NT times.
template <bool ACT, bool W8, int BK>
__launch_bounds__(256, 3)
__global__ void gemm1p(const unsigned short* __restrict__ Ah,
                       const unsigned short* __restrict__ A2h,
                       int lda, int lda2, int ksplit,
                       const unsigned short* __restrict__ Bh,
                       int ldb, const float* __restrict__ bias,
                       unsigned short* __restrict__ Chi,
                       unsigned char* __restrict__ C8,
                       int ldc, int M, int K, int NT) {
  const int lin = blockIdx.x;
  const int xcd = lin & 7;
  const int seq = lin >> 3;
  const int bn = seq % NT;
  const int bm = xcd + 8 * (seq / NT);
  if (bm * 128 >= M) return;

  constexpr int CT_LD = 136;
  constexpr int STAGE_B = 2 * 128 * BK * 2;
  constexpr int CT_B = 128 * CT_LD * 2;
  constexpr int C8_B = W8 ? 128 * CT_LD : 0;
  constexpr int SMEM_B = (STAGE_B > CT_B + C8_B) ? STAGE_B : (CT_B + C8_B);
  __shared__ __align__(16) unsigned char smem[SMEM_B];
  unsigned short* Ash = (unsigned short*)smem;
  unsigned short* Bsh = Ash + 128 * BK;
  const int t = threadIdx.x;
  const int l = t & 63;
  const int w = t >> 6;
  const int wm = w >> 1, wn = w & 1;
  const int lrow = l & 15, lk = (l >> 4) * 8;

  f32x4 acc[4][4] = {};

  const int arow0 = bm * 128;
  const int brow0 = bn * 128;

  for (int k0 = 0; k0 < K; k0 += BK) {
    const bool first = k0 < ksplit;
    const unsigned short* Abase = first ? Ah : A2h;
    const int acol = first ? k0 : (k0 - ksplit);
    const int alda = first ? lda : lda2;
    __syncthreads();
#pragma unroll
    for (int it = 0; it < BK / 16; it++) {
      int c = t + it * 256;
      int row = c / (BK / 8);
      int sk = (c % (BK / 8)) * 8;
      int ar = arow0 + row;
      if (ar >= M) ar = M - 1;
      int ldst = row * BK + sk;     // lane*16B from wave-uniform base (layout law m104)
      GLD16(Abase + (long)ar * alda + acol + sk, Ash + ldst);
      GLD16(Bh + (long)(brow0 + row) * ldb + k0 + sk, Bsh + ldst);
    }
    __syncthreads();
#pragma unroll
    for (int kk = 0; kk < BK / 32; kk++) {
      short8 ah[4], bh4[4];
#pragma unroll
      for (int m = 0; m < 4; m++)
        ah[m] = *(const short8*)(Ash + (wm * 64 + m * 16 + lrow) * BK + kk * 32 + lk);
#pragma unroll
      for (int n = 0; n < 4; n++)
        bh4[n] = *(const short8*)(Bsh + (wn * 64 + n * 16 + lrow) * BK + kk * 32 + lk);
#pragma unroll
      for (int m = 0; m < 4; m++)
#pragma unroll
        for (int n = 0; n < 4; n++)
          acc[m][n] = __builtin_amdgcn_mfma_f32_16x16x32_bf16(ah[m], bh4[n], acc[m][n], 0, 0, 0);
    }
  }

  // ---- epilogue: repack through LDS, then coalesced stores ----
  __syncthreads();                         // all staging reads done before overlay
  unsigned short* Ct = (unsigned short*)smem;
  unsigned char* C8t = smem + CT_B;
  const int orl = wm * 64 + (l >> 4) * 4;
  const int ocl = wn * 64 + lrow;
#pragma unroll
  for (int n = 0; n < 4; n++) {
    float bv = bias[bn * 128 + ocl + n * 16];
#pragma unroll
    for (int m = 0; m < 4; m++) {
#pragma unroll
      for (int ri = 0; ri < 4; ri++) {
        float v = acc[m][n][ri] + bv;
        if constexpr (ACT) v = v > 0.f ? v : 0.1f * v;
        int rr = orl + m * 16 + ri, cc = ocl + n * 16;
        Ct[rr * CT_LD + cc] = f2b(v);
        if constexpr (W8) C8t[rr * CT_LD + cc] = f2e4m3(v);  // fp8 from original f32
      }
    }
  }
  __syncthreads();
  const long row0 = bm * 128;
  const long col0 = bn * 128;
#pragma unroll
  for (int p = 0; p < 8; p++) {
    int idx = t + p * 256;
    int r = idx >> 4, cb = (idx & 15) * 8;
    long gr = row0 + r;
    if (gr < M)
      *(short8*)(Chi + gr * ldc + col0 + cb) = *(const short8*)(Ct + r * CT_LD + cb);
  }
  if constexpr (W8) {
#pragma unroll
    for (int p = 0; p < 8; p++) {
      int idx = t + p * 256;
      int r = idx >> 4, cb = (idx & 15) * 8;
      long gr = row0 + r;
      if (gr < M)
        *(uint2*)(C8 + gr * ldc + col0 + cb) = *(const uint2*)(C8t + r * CT_LD + cb);
    }
  }
}

// ---------------- multi-pass MFMA GEMM (in_proj / out): round-10 structure ----------------
template <int WMODE, bool AL, bool BL, bool ACC, bool W8, int OCC, int BK>
__launch_bounds__(256, OCC)
__global__ void gemmx(const unsigned short* __restrict__ Ah,
                      const unsigned short* __restrict__ Al,
                      int lda,
                      const unsigned short* __restrict__ Bh,
                      const unsigned short* __restrict__ Bl,
                      int ldb, const float* __restrict__ bias,
                      float* __restrict__ Cf,
                      unsigned short* __restrict__ Chi,
                      unsigned char* __restrict__ C8,
                      int ldc, int M, int K) {
  __shared__ __align__(16) unsigned short Ash[128 * BK];
  __shared__ __align__(16) unsigned short Asl[AL ? 128 * BK : 16];
  __shared__ __align__(16) unsigned short Bsh[128 * BK];
  __shared__ __align__(16) unsigned short Bsl[BL ? 128 * BK : 16];
  const int t = threadIdx.x;
  const int bm = blockIdx.x, bn = blockIdx.y;
  const int l = t & 63;
  const int w = t >> 6;
  const int wm = w >> 1, wn = w & 1;
  const int lrow = l & 15, lk = (l >> 4) * 8;

  f32x4 acc[4][4] = {};

  const int arow0 = bm * 128;
  const int brow0 = bn * 128;

  for (int k0 = 0; k0 < K; k0 += BK) {
    __syncthreads();
#pragma unroll
    for (int it = 0; it < BK / 16; it++) {
      int c = t + it * 256;
      int row = c / (BK / 8);
      int sk = (c % (BK / 8)) * 8;
      int ar = arow0 + row;
      if (ar >= M) ar = M - 1;
      long boff = (long)(brow0 + row) * ldb + k0 + sk;
      int ldst = row * BK + sk;
      GLD16(Ah + (long)ar * lda + k0 + sk, Ash + ldst);
      if (AL) GLD16(Al + (long)ar * lda + k0 + sk, Asl + ldst);
      GLD16(Bh + boff, Bsh + ldst);
      if (BL) GLD16(Bl + boff, Bsl + ldst);
    }
    __syncthreads();
#pragma unroll
    for (int kk = 0; kk < BK / 32; kk++) {
      short8 ah[4], al4[4], bh[4], bl4[4];
#pragma unroll
      for (int m = 0; m < 4; m++) {
        int ro = (wm * 64 + m * 16 + lrow) * BK + kk * 32 + lk;
        ah[m] = *(const short8*)(Ash + ro);
        if (AL) al4[m] = *(const short8*)(Asl + ro);
      }
#pragma unroll
      for (int n = 0; n < 4; n++) {
        int ro = (wn * 64 + n * 16 + lrow) * BK + kk * 32 + lk;
        bh[n] = *(const short8*)(Bsh + ro);
        if (BL) bl4[n] = *(const short8*)(Bsl + ro);
      }
#pragma unroll
      for (int m = 0; m < 4; m++)
#pragma unroll
        for (int n = 0; n < 4; n++) {
          acc[m][n] = __builtin_amdgcn_mfma_f32_16x16x32_bf16(ah[m], bh[n], acc[m][n], 0, 0, 0);
          if (BL)
            acc[m][n] = __builtin_amdgcn_mfma_f32_16x16x32_bf16(ah[m], bl4[n], acc[m][n], 0, 0, 0);
          if (AL)
            acc[m][n] = __builtin_amdgcn_mfma_f32_16x16x32_bf16(al4[m], bh[n], acc[m][n], 0, 0, 0);
        }
    }
  }

  const int orow0 = bm * 128 + wm * 64 + (l >> 4) * 4;
  const int ocol0 = bn * 128 + wn * 64 + lrow;
#pragma unroll
  for (int n = 0; n < 4; n++) {
    int gc = ocol0 + n * 16;
    float bv;
    if constexpr (ACC) bv = 0.f; else bv = bias[gc];
#pragma unroll
    for (int m = 0; m < 4; m++) {
#pragma unroll
      for (int ri = 0; ri < 4; ri++) {
        int gr = orow0 + m * 16 + ri;
        if (gr < M) {
          float v = acc[m][n][ri] + bv;
          if constexpr (ACC) v += Cf[(long)gr * ldc + gc];
          if constexpr (WMODE == 0) {
            Cf[(long)gr * ldc + gc] = v;
          } else {
            Chi[(long)gr * ldc + gc] = f2b(v);
            if constexpr (W8) C8[(long)gr * ldc + gc] = f2e4m3(v);
          }
        }
      }
    }
  }
}

// ---------------- host ----------------
extern "C" void kernel_launch(void* const* d_in, const int* in_sizes, int n_in,
                              void* d_out, int out_size, void* d_ws, size_t ws_size,
                              hipStream_t stream) {
  const float* x = (const float*)d_in[0];
  const int* ei = (const int*)d_in[1];
  const int E = in_sizes[1] / 2;
  const int* src = ei;
  const int* dst = ei + E;
  const float* in_w = (const float*)d_in[2];
  const float* in_b = (const float*)d_in[3];
  const float* w1 = (const float*)d_in[4];
  const float* b1 = (const float*)d_in[5];
  const float* ln_g = (const float*)d_in[6];
  const float* ln_b = (const float*)d_in[7];
  const float* w2 = (const float*)d_in[8];
  const float* b2 = (const float*)d_in[9];
  const float* w3 = (const float*)d_in[10];
  const float* b3 = (const float*)d_in[11];
  const float* out_w = (const float*)d_in[12];
  const float* out_b = (const float*)d_in[13];
  float* out = (float*)d_out;

  char* ws = (char*)d_ws;
  size_t off = 0;
  auto alloc = [&](size_t bytes) -> void* {
    void* p = ws + off;
    off += (bytes + 255) & ~(size_t)255;
    return p;
  };
  // ---- layout (~251 MB, ws is 256 MiB) ----
  int* rowptr = (int*)alloc((NN + 1) * 4);
  int* cursor = (int*)alloc((size_t)NN * 4);
  int* cols = (int*)alloc((size_t)E * 4);
  int* sums = (int*)alloc(1024);
  int* sums2 = (int*)alloc(256);
  unsigned short* in_wb_h = (unsigned short*)alloc((size_t)HD * DIN * 2);
  unsigned short* in_wb_l = (unsigned short*)alloc((size_t)HD * DIN * 2);
  unsigned short* w1b = (unsigned short*)alloc(2ul * DMID * DCAT * 2);
  unsigned short* w2b = (unsigned short*)alloc(2ul * DMID * DMID * 2);
  unsigned short* w3b = (unsigned short*)alloc(2ul * HD * DMID * 2);
  unsigned short* out_wb_h = (unsigned short*)alloc((size_t)DOUT * DSUM * 2);
  unsigned short* out_wb_l = (unsigned short*)alloc((size_t)DOUT * DSUM * 2);
  unsigned short* xpart = (unsigned short*)alloc((size_t)NN * DIN * 2);   // 25.6 MB
  unsigned short* h = (unsigned short*)alloc((size_t)NN * HD * 2);        // 51.2 MB
  unsigned char* h8 = (unsigned char*)alloc((size_t)NN * HD);             // 25.6 MB
  unsigned short* hpart = (unsigned short*)alloc((size_t)NN * HD * 2);    // 51.2 MB
  unsigned short* h1c = (unsigned short*)alloc((size_t)CH * DMID * 2);    // 39.3 MB
  unsigned short* h2c = (unsigned short*)alloc((size_t)CH * DMID * 2);    // 39.3 MB
  const size_t need = off;

  if (need > ws_size) {
    sentinel_fill<<<2048, 256, 0, stream>>>(out, (long)NN * DOUT, (float)ws_size);
    return;
  }

  // Aliases (dead-range reuse, safe by stream order):
  //  - x hi/lo split lives in hpart until first agg_h.
  //  - x8 fp8 copy lives in h1c until first GEMM1.
  unsigned short* xb_h = hpart;
  unsigned short* xb_l = hpart + (size_t)NN * DIN;
  unsigned char* x8 = (unsigned char*)h1c;

  hipMemsetAsync(rowptr, 0, (NN + 1) * 4, stream);
  hipMemsetAsync(cursor, 0, (size_t)NN * 4, stream);

  const int eb = (E + 255) / 256;
  const int nscan = NN + 1;
  const int nsb = (nscan + 255) / 256;

  deg_kernel<<<eb, 256, 0, stream>>>(dst, E, rowptr);
  scan_block<<<nsb, 256, 0, stream>>>(rowptr, nscan, sums);
  scan_block<<<1, 256, 0, stream>>>(sums, nsb, sums2);
  scan_add<<<nsb, 256, 0, stream>>>(rowptr, nscan, sums);
  fill_kernel<<<eb, 256, 0, stream>>>(src, dst, E, rowptr, cursor, cols);

  cast_split8_kernel<<<2048, 256, 0, stream>>>(x, xb_h, xb_l, x8, (long)NN * DIN / 4);
  cast_transpose_kernel<true><<<dim3(DIN / 32, HD / 32, 1), 256, 0, stream>>>(in_w, in_wb_h, in_wb_l, DIN, HD);
  cast_transpose_kernel<false><<<dim3(DCAT / 32, DMID / 32, 2), 256, 0, stream>>>(w1, w1b, nullptr, DCAT, DMID);
  cast_transpose_kernel<false><<<dim3(DMID / 32, DMID / 32, 2), 256, 0, stream>>>(w2, w2b, nullptr, DMID, DMID);
  cast_transpose_kernel<false><<<dim3(DMID / 32, HD / 32, 2), 256, 0, stream>>>(w3, w3b, nullptr, DMID, HD);
  cast_transpose_kernel<true><<<dim3(DSUM / 32, DOUT / 32, 1), 256, 0, stream>>>(out_w, out_wb_h, out_wb_l, DSUM, DOUT);

  const int MT = (NN + 127) / 128;  // 391
  const int AGB = NN / 4;           // 12500 blocks, wave-per-node

  // in_proj: h0 = bf16(x@in_w + in_b), + fp8 copy  (A hi/lo, B hi/lo: 3 passes, BK=64)
  gemmx<1, true, true, false, true, 2, 64><<<dim3(MT, HD / 128), 256, 0, stream>>>(
      xb_h, xb_l, DIN, in_wb_h, in_wb_l, DIN, in_b,
      nullptr, h, h8, HD, NN, DIN);

  // xpart = bf16(xb + A@x8)   (iteration-invariant; reads xb/x8 aliases)
  agg_x_kernel<<<AGB, 256, 0, stream>>>(xb_h, x8, rowptr, cols, xpart);

  // out = out_b + h0 @ out_w[0:512]   (B hi/lo: 2 passes, BK=64)
  gemmx<0, false, true, false, false, 2, 64><<<dim3(MT, DOUT / 128), 256, 0, stream>>>(
      h, nullptr, HD, out_wb_h, out_wb_l, DSUM, out_b,
      out, nullptr, nullptr, DOUT, NN, HD);

  for (int i = 0; i < 2; i++) {
    // hpart = bf16(h_i + A@h8_i)  (clobbers xb alias — xb dead by now)
    agg_h_kernel<<<AGB, 256, 0, stream>>>(h, h8, rowptr, cols, hpart);

    // MLP chunked over rows; GEMM3 writes h_{i+1} (+fp8) in place over h
    for (int r0 = 0; r0 < NN; r0 += CH) {
      int Mc = NN - r0 < CH ? NN - r0 : CH;
      int MTc = (Mc + 127) / 128;
      int MT8 = ((MTc + 7) / 8) * 8;
      // GEMM1: A split = [xpart | hpart], K=768, BK=64, XCD-grouped
      gemm1p<false, false, 64><<<MT8 * (DMID / 128), 256, 0, stream>>>(
          xpart + (size_t)r0 * DIN, hpart + (size_t)r0 * HD, DIN, HD, DIN,
          w1b + (size_t)i * DMID * DCAT, DCAT,
          b1 + i * DMID, h1c, nullptr, DMID, Mc, DCAT, DMID / 128);
      ln_leaky_kernel<<<Mc, 256, 0, stream>>>(h1c, ln_g + i * DMID, ln_b + i * DMID);
      // GEMM2: fused leaky, BK=64, XCD-grouped
      gemm1p<true, false, 64><<<MT8 * (DMID / 128), 256, 0, stream>>>(
          h1c, h1c, DMID, DMID, 1 << 30,
          w2b + (size_t)i * DMID * DMID, DMID,
          b2 + i * DMID, h2c, nullptr, DMID, Mc, DMID, DMID / 128);
      // GEMM3: writes h_{i+1} bf16 + fp8, BK=64, XCD-grouped
      gemm1p<false, true, 64><<<MT8 * (HD / 128), 256, 0, stream>>>(
          h2c, h2c, DMID, DMID, 1 << 30,
          w3b + (size_t)i * HD * DMID, DMID,
          b3 + i * HD, h + (size_t)r0 * HD, h8 + (size_t)r0 * HD, HD, Mc, DMID, HD / 128);
    }

    // out += h_{i+1} @ out_w[512*(i+1) : 512*(i+2)]   (B hi/lo: 2 passes, BK=64)
    gemmx<0, false, true, true, false, 2, 64><<<dim3(MT, DOUT / 128), 256, 0, stream>>>(
        h, nullptr, HD,
        out_wb_h + (size_t)(i + 1) * HD, out_wb_l + (size_t)(i + 1) * HD, DSUM,
        nullptr, out, nullptr, nullptr, DOUT, NN, HD);
  }
}

// Round 14
// 1686.694 us; speedup vs baseline: 1.2985x; 1.0182x over previous
//
#include <hip/hip_runtime.h>
#include <hip/hip_bf16.h>

#define NN 50000
#define DIN 256
#define HD 512
#define DCAT 768
#define DMID 1024
#define DSUM 1536
#define DOUT 256
#define CH 19200
#define LN_EPS 1e-5f

typedef __attribute__((ext_vector_type(8))) short short8;
typedef __attribute__((ext_vector_type(4))) float f32x4;
typedef __attribute__((ext_vector_type(2))) float f32x2;

__device__ __forceinline__ unsigned short f2b(float f) {
  unsigned int u = __float_as_uint(f);
  u += 0x7FFF + ((u >> 16) & 1);   // round-to-nearest-even
  return (unsigned short)(u >> 16);
}
__device__ __forceinline__ float b2f(unsigned short s) {
  return __uint_as_float(((unsigned int)s) << 16);
}
__device__ __forceinline__ void splitbf(float v, unsigned short& hi, unsigned short& lo) {
  hi = f2b(v);
  lo = f2b(v - b2f(hi));
}
// fp8 e4m3 encode (hardware, saturating)
__device__ __forceinline__ unsigned char f2e4m3(float v) {
  return (unsigned char)(__builtin_amdgcn_cvt_pk_fp8_f32(v, v, 0, false) & 0xff);
}

// ---------------- diagnostic fill ----------------
__global__ void sentinel_fill(float* __restrict__ out, long n, float v) {
  for (long i = (long)blockIdx.x * blockDim.x + threadIdx.x; i < n;
       i += (long)gridDim.x * blockDim.x)
    out[i] = v;
}

// ---------------- casts / splits ----------------
// x -> bf16 hi/lo + fp8 in one pass
__global__ void cast_split8_kernel(const float* __restrict__ in,
                                   unsigned short* __restrict__ oh,
                                   unsigned short* __restrict__ ol,
                                   unsigned char* __restrict__ o8, long n4) {
  for (long i = (long)blockIdx.x * blockDim.x + threadIdx.x; i < n4;
       i += (long)gridDim.x * blockDim.x) {
    float4 v = ((const float4*)in)[i];
    ushort4 h, l;
    splitbf(v.x, h.x, l.x); splitbf(v.y, h.y, l.y);
    splitbf(v.z, h.z, l.z); splitbf(v.w, h.w, l.w);
    ((ushort4*)oh)[i] = h;
    ((ushort4*)ol)[i] = l;
    unsigned int r = __builtin_amdgcn_cvt_pk_fp8_f32(v.x, v.y, 0, false);
    r = __builtin_amdgcn_cvt_pk_fp8_f32(v.z, v.w, r, true);
    ((unsigned int*)o8)[i] = r;
  }
}

// in: [K][N] f32 -> out hi(/lo): [N][K] bf16  (K,N multiples of 32). blockIdx.z = matrix idx
template <bool SPLIT>
__global__ void cast_transpose_kernel(const float* __restrict__ in,
                                      unsigned short* __restrict__ oh,
                                      unsigned short* __restrict__ ol, int K, int N) {
  const float* src = in + (long)blockIdx.z * K * N;
  unsigned short* dh = oh + (long)blockIdx.z * K * N;
  unsigned short* dl = SPLIT ? ol + (long)blockIdx.z * K * N : nullptr;
  __shared__ unsigned short th[32][33];
  __shared__ unsigned short tl[SPLIT ? 32 : 1][33];
  int bk = blockIdx.x * 32, bn = blockIdx.y * 32;
  int tx = threadIdx.x & 31, ty = threadIdx.x >> 5;
#pragma unroll
  for (int i = ty; i < 32; i += 8) {
    float v = src[(long)(bk + i) * N + bn + tx];
    if (SPLIT) {
      unsigned short h, l;
      splitbf(v, h, l);
      th[i][tx] = h; tl[i][tx] = l;
    } else {
      th[i][tx] = f2b(v);
    }
  }
  __syncthreads();
#pragma unroll
  for (int i = ty; i < 32; i += 8) {
    dh[(long)(bn + i) * K + bk + tx] = th[tx][i];
    if (SPLIT) dl[(long)(bn + i) * K + bk + tx] = tl[tx][i];
  }
}

// ---------------- CSR build ----------------
__global__ void deg_kernel(const int* __restrict__ dst, int E, int* __restrict__ rowptr) {
  int i = blockIdx.x * blockDim.x + threadIdx.x;
  if (i < E) atomicAdd(&rowptr[dst[i] + 1], 1);
}

__global__ void scan_block(int* __restrict__ data, int n, int* __restrict__ sums) {
  __shared__ int tmp[2][256];
  int i = blockIdx.x * 256 + threadIdx.x;
  int v = (i < n) ? data[i] : 0;
  int pp = 0;
  tmp[0][threadIdx.x] = v;
  __syncthreads();
#pragma unroll
  for (int off = 1; off < 256; off <<= 1) {
    int t2 = tmp[pp][threadIdx.x];
    if (threadIdx.x >= off) t2 += tmp[pp][threadIdx.x - off];
    tmp[pp ^ 1][threadIdx.x] = t2;
    pp ^= 1;
    __syncthreads();
  }
  if (i < n) data[i] = tmp[pp][threadIdx.x];
  if (threadIdx.x == 255) sums[blockIdx.x] = tmp[pp][255];
}

__global__ void scan_add(int* __restrict__ data, int n, const int* __restrict__ sums) {
  int i = blockIdx.x * 256 + threadIdx.x;
  if (blockIdx.x > 0 && i < n) data[i] += sums[blockIdx.x - 1];
}

__global__ void fill_kernel(const int* __restrict__ src, const int* __restrict__ dst, int E,
                            const int* __restrict__ rowptr, int* __restrict__ cursor,
                            int* __restrict__ cols) {
  int i = blockIdx.x * blockDim.x + threadIdx.x;
  if (i < E) {
    int r = dst[i];
    int p = rowptr[r] + atomicAdd(&cursor[r], 1);
    cols[p] = src[i];
  }
}

// ---------------- aggregation (wave-per-node; fp8 neighbor gather; round-8 proven) ----------------
// xpart[i,:] = bf16(xb_i + sum_j x8_j)  (own bf16, neighbors fp8 256B/row)
__global__ void agg_x_kernel(const unsigned short* __restrict__ xb,
                             const unsigned char* __restrict__ x8,
                             const int* __restrict__ rowptr,
                             const int* __restrict__ cols,
                             unsigned short* __restrict__ xpart) {
  int node = blockIdx.x * 4 + (threadIdx.x >> 6);
  int lane = threadIdx.x & 63;
  ushort4 own = *((const ushort4*)(xb + (long)node * DIN) + lane);
  float s0 = b2f(own.x), s1 = b2f(own.y), s2 = b2f(own.z), s3 = b2f(own.w);
  int e0 = rowptr[node], e1 = rowptr[node + 1];
  int p = e0;
#define XACC(w)                                                   \
  {                                                               \
    f32x2 t0 = __builtin_amdgcn_cvt_pk_f32_fp8((w), false);       \
    f32x2 t1 = __builtin_amdgcn_cvt_pk_f32_fp8((w), true);        \
    s0 += t0.x; s1 += t0.y; s2 += t1.x; s3 += t1.y;               \
  }
  for (; p + 3 < e1; p += 4) {
    int j0 = cols[p], j1 = cols[p + 1], j2 = cols[p + 2], j3 = cols[p + 3];
    unsigned int a = *((const unsigned int*)(x8 + (long)j0 * DIN) + lane);
    unsigned int b = *((const unsigned int*)(x8 + (long)j1 * DIN) + lane);
    unsigned int c = *((const unsigned int*)(x8 + (long)j2 * DIN) + lane);
    unsigned int d = *((const unsigned int*)(x8 + (long)j3 * DIN) + lane);
    XACC(a); XACC(b); XACC(c); XACC(d);
  }
  for (; p < e1; p++) {
    unsigned int a = *((const unsigned int*)(x8 + (long)cols[p] * DIN) + lane);
    XACC(a);
  }
#undef XACC
  ushort4 o;
  o.x = f2b(s0); o.y = f2b(s1); o.z = f2b(s2); o.w = f2b(s3);
  *((ushort4*)(xpart + (long)node * DIN) + lane) = o;
}

// hpart[i,:] = bf16(h_i + sum_j h8_j)  (own bf16 1KB, neighbors fp8 512B/row)
__global__ void agg_h_kernel(const unsigned short* __restrict__ h,
                             const unsigned char* __restrict__ h8,
                             const int* __restrict__ rowptr, const int* __restrict__ cols,
                             unsigned short* __restrict__ hpart) {
  int node = blockIdx.x * 4 + (threadIdx.x >> 6);
  int lane = threadIdx.x & 63;
  short8 own = *((const short8*)(h + (long)node * HD) + lane);
  float s[8];
#pragma unroll
  for (int q = 0; q < 8; q++) s[q] = b2f((unsigned short)own[q]);
  int e0 = rowptr[node], e1 = rowptr[node + 1];
  int p = e0;
#define HACC(w)                                                   \
  {                                                               \
    f32x2 t0 = __builtin_amdgcn_cvt_pk_f32_fp8((w).x, false);     \
    f32x2 t1 = __builtin_amdgcn_cvt_pk_f32_fp8((w).x, true);      \
    f32x2 t2 = __builtin_amdgcn_cvt_pk_f32_fp8((w).y, false);     \
    f32x2 t3 = __builtin_amdgcn_cvt_pk_f32_fp8((w).y, true);      \
    s[0] += t0.x; s[1] += t0.y; s[2] += t1.x; s[3] += t1.y;       \
    s[4] += t2.x; s[5] += t2.y; s[6] += t3.x; s[7] += t3.y;       \
  }
  for (; p + 3 < e1; p += 4) {
    int j0 = cols[p], j1 = cols[p + 1], j2 = cols[p + 2], j3 = cols[p + 3];
    uint2 a = *((const uint2*)(h8 + (long)j0 * HD) + lane);
    uint2 b = *((const uint2*)(h8 + (long)j1 * HD) + lane);
    uint2 c = *((const uint2*)(h8 + (long)j2 * HD) + lane);
    uint2 d = *((const uint2*)(h8 + (long)j3 * HD) + lane);
    HACC(a); HACC(b); HACC(c); HACC(d);
  }
  for (; p < e1; p++) {
    uint2 a = *((const uint2*)(h8 + (long)cols[p] * HD) + lane);
    HACC(a);
  }
#undef HACC
  short8 o;
#pragma unroll
  for (int q = 0; q < 8; q++) o[q] = (short)f2b(s[q]);
  *((short8*)(hpart + (long)node * HD) + lane) = o;
}

// ---------------- LayerNorm + leaky on bf16 rows of width 1024 (in place) ----------------
__global__ void ln_leaky_kernel(unsigned short* __restrict__ arr,
                                const float* __restrict__ gamma,
                                const float* __restrict__ beta) {
  int row = blockIdx.x, t = threadIdx.x;
  unsigned short* p = arr + (long)row * DMID;
  ushort4 u = ((const ushort4*)p)[t];
  float v0 = b2f(u.x), v1 = b2f(u.y), v2 = b2f(u.z), v3 = b2f(u.w);
  float s = v0 + v1 + v2 + v3;
  float sq = v0 * v0 + v1 * v1 + v2 * v2 + v3 * v3;
#pragma unroll
  for (int off = 32; off >= 1; off >>= 1) {
    s += __shfl_down(s, off, 64);
    sq += __shfl_down(sq, off, 64);
  }
  __shared__ float red[8];
  int w = t >> 6, lane = t & 63;
  if (lane == 0) { red[w] = s; red[4 + w] = sq; }
  __syncthreads();
  s = red[0] + red[1] + red[2] + red[3];
  sq = red[4] + red[5] + red[6] + red[7];
  float mean = s * (1.f / DMID);
  float var = sq * (1.f / DMID) - mean * mean;
  float rstd = rsqrtf(var + LN_EPS);
  float4 gv = ((const float4*)gamma)[t];
  float4 bv = ((const float4*)beta)[t];
  float o0 = (v0 - mean) * rstd * gv.x + bv.x;
  float o1 = (v1 - mean) * rstd * gv.y + bv.y;
  float o2 = (v2 - mean) * rstd * gv.z + bv.z;
  float o3 = (v3 - mean) * rstd * gv.w + bv.w;
  o0 = o0 > 0.f ? o0 : 0.1f * o0;
  o1 = o1 > 0.f ? o1 : 0.1f * o1;
  o2 = o2 > 0.f ? o2 : 0.1f * o2;
  o3 = o3 > 0.f ? o3 : 0.1f * o3;
  ushort4 ou;
  ou.x = f2b(o0); ou.y = f2b(o1); ou.z = f2b(o2); ou.w = f2b(o3);
  ((ushort4*)p)[t] = ou;
}

#define GLD16(src, dst)                                                          \
  __builtin_amdgcn_global_load_lds(                                              \
      (const __attribute__((address_space(1))) void*)(src),                      \
      (__attribute__((address_space(3))) void*)(dst), 16, 0, 0)

// LDS chunk swizzle (chunk = 16B = 8 bf16). Rule #21: linear LDS dest via
// global_load_lds; the SOURCE address carries the inverse permutation; reads
// apply the same XOR. BK=64 rows (128B): ch ^ (row&7) -> 32 banks, 2-way.
// BK=32 rows (64B): ch ^ ((row>>1)&3) + natural row-parity -> 8 slots, 2-way.
template <int BK>
__device__ __forceinline__ int swz(int row, int ch) {
  if constexpr (BK == 64) return ch ^ (row & 7);
  else return ch ^ ((row >> 1) & 3);
}

// ---------------- 1-pass conv GEMM: BK=32 double-buffer + T2 swizzle + repack epilogue ----------------
// 128x128 tile, 4 waves (2x2), OCC=3 (dbuf LDS 32KB). XCD-grouped 1-D grid.
// Per iter: STAGE(next) -> compute(cur) -> barrier. Bit-identical numerics.
template <bool ACT, bool W8, int BK>
__launch_bounds__(256, 3)
__global__ void gemm1p(const unsigned short* __restrict__ Ah,
                       const unsigned short* __restrict__ A2h,
                       int lda, int lda2, int ksplit,
                       const unsigned short* __restrict__ Bh,
                       int ldb, const float* __restrict__ bias,
                       unsigned short* __restrict__ Chi,
                       unsigned char* __restrict__ C8,
                       int ldc, int M, int K, int NT) {
  const int lin = blockIdx.x;
  const int xcd = lin & 7;
  const int seq = lin >> 3;
  const int bn = seq % NT;
  const int bm = xcd + 8 * (seq / NT);
  if (bm * 128 >= M) return;

  constexpr int CT_LD = 136;
  constexpr int TILE = 128 * BK;                 // elems per matrix per buf
  constexpr int STAGE_B = 2 * 2 * TILE * 2;      // 2 bufs x (A,B) x 2B
  constexpr int CT_B = 128 * CT_LD * 2;
  constexpr int C8_B = W8 ? 128 * CT_LD : 0;
  constexpr int SMEM_B = (STAGE_B > CT_B + C8_B) ? STAGE_B : (CT_B + C8_B);
  __shared__ __align__(16) unsigned char smem[SMEM_B];
  unsigned short* Ash = (unsigned short*)smem;       // [2][TILE]
  unsigned short* Bsh = Ash + 2 * TILE;              // [2][TILE]
  const int t = threadIdx.x;
  const int l = t & 63;
  const int w = t >> 6;
  const int wm = w >> 1, wn = w & 1;
  const int lrow = l & 15;

  f32x4 acc[4][4] = {};

  const int arow0 = bm * 128;
  const int brow0 = bn * 128;
  constexpr int CPR = BK / 8;                    // chunks per row

  auto STAGE = [&](int buf, int k0) {
    const bool first = k0 < ksplit;
    const unsigned short* Abase = first ? Ah : A2h;
    const int acol = first ? k0 : (k0 - ksplit);
    const int alda = first ? lda : lda2;
#pragma unroll
    for (int it = 0; it < BK / 16; it++) {
      int c = t + it * 256;
      int row = c / CPR;
      int pc = c % CPR;
      int lc = swz<BK>(row, pc);                 // inverse-swizzled source chunk
      int ar = arow0 + row;
      if (ar >= M) ar = M - 1;
      int ldst = buf * TILE + c * 8;             // linear: lane*16B from wave base
      GLD16(Abase + (long)ar * alda + acol + lc * 8, Ash + ldst);
      GLD16(Bh + (long)(brow0 + row) * ldb + k0 + lc * 8, Bsh + ldst);
    }
  };

  const int nt = K / BK;
  STAGE(0, 0);
  __syncthreads();
  int cur = 0;
  for (int tk = 0; tk < nt; tk++) {
    if (tk + 1 < nt) STAGE(cur ^ 1, (tk + 1) * BK);
#pragma unroll
    for (int kk = 0; kk < BK / 32; kk++) {
      const int ph = swz<BK>(lrow, kk * 4 + (l >> 4));   // row&7 / (row>>1)&3 reduce to lrow bits
      short8 ah[4], bh4[4];
#pragma unroll
      for (int m = 0; m < 4; m++)
        ah[m] = *(const short8*)(Ash + cur * TILE + (wm * 64 + m * 16 + lrow) * BK + ph * 8);
#pragma unroll
      for (int n = 0; n < 4; n++)
        bh4[n] = *(const short8*)(Bsh + cur * TILE + (wn * 64 + n * 16 + lrow) * BK + ph * 8);
#pragma unroll
      for (int m = 0; m < 4; m++)
#pragma unroll
        for (int n = 0; n < 4; n++)
          acc[m][n] = __builtin_amdgcn_mfma_f32_16x16x32_bf16(ah[m], bh4[n], acc[m][n], 0, 0, 0);
    }
    __syncthreads();
    cur ^= 1;
  }

  // ---- epilogue: repack through LDS, then coalesced stores ----
  __syncthreads();
  unsigned short* Ct = (unsigned short*)smem;
  unsigned char* C8t = smem + CT_B;
  const int orl = wm * 64 + (l >> 4) * 4;
  const int ocl = wn * 64 + lrow;
#pragma unroll
  for (int n = 0; n < 4; n++) {
    float bv = bias[bn * 128 + ocl + n * 16];
#pragma unroll
    for (int m = 0; m < 4; m++) {
#pragma unroll
      for (int ri = 0; ri < 4; ri++) {
        float v = acc[m][n][ri] + bv;
        if constexpr (ACT) v = v > 0.f ? v : 0.1f * v;
        int rr = orl + m * 16 + ri, cc = ocl + n * 16;
        Ct[rr * CT_LD + cc] = f2b(v);
        if constexpr (W8) C8t[rr * CT_LD + cc] = f2e4m3(v);
      }
    }
  }
  __syncthreads();
  const long row0 = bm * 128;
  const long col0 = bn * 128;
#pragma unroll
  for (int p = 0; p < 8; p++) {
    int idx = t + p * 256;
    int r = idx >> 4, cb = (idx & 15) * 8;
    long gr = row0 + r;
    if (gr < M)
      *(short8*)(Chi + gr * ldc + col0 + cb) = *(const short8*)(Ct + r * CT_LD + cb);
  }
  if constexpr (W8) {
#pragma unroll
    for (int p = 0; p < 8; p++) {
      int idx = t + p * 256;
      int r = idx >> 4, cb = (idx & 15) * 8;
      long gr = row0 + r;
      if (gr < M)
        *(uint2*)(C8 + gr * ldc + col0 + cb) = *(const uint2*)(C8t + r * CT_LD + cb);
    }
  }
}

// ---------------- multi-pass MFMA GEMM (in_proj / out): 2-barrier + T2 swizzle ----------------
template <int WMODE, bool AL, bool BL, bool ACC, bool W8, int OCC, int BK>
__launch_bounds__(256, OCC)
__global__ void gemmx(const unsigned short* __restrict__ Ah,
                      const unsigned short* __restrict__ Al,
                      int lda,
                      const unsigned short* __restrict__ Bh,
                      const unsigned short* __restrict__ Bl,
                      int ldb, const float* __restrict__ bias,
                      float* __restrict__ Cf,
                      unsigned short* __restrict__ Chi,
                      unsigned char* __restrict__ C8,
                      int ldc, int M, int K) {
  __shared__ __align__(16) unsigned short Ash[128 * BK];
  __shared__ __align__(16) unsigned short Asl[AL ? 128 * BK : 16];
  __shared__ __align__(16) unsigned short Bsh[128 * BK];
  __shared__ __align__(16) unsigned short Bsl[BL ? 128 * BK : 16];
  const int t = threadIdx.x;
  const int bm = blockIdx.x, bn = blockIdx.y;
  const int l = t & 63;
  const int w = t >> 6;
  const int wm = w >> 1, wn = w & 1;
  const int lrow = l & 15;
  constexpr int CPR = BK / 8;

  f32x4 acc[4][4] = {};

  const int arow0 = bm * 128;
  const int brow0 = bn * 128;

  for (int k0 = 0; k0 < K; k0 += BK) {
    __syncthreads();
#pragma unroll
    for (int it = 0; it < BK / 16; it++) {
      int c = t + it * 256;
      int row = c / CPR;
      int pc = c % CPR;
      int lc = swz<BK>(row, pc);
      int ar = arow0 + row;
      if (ar >= M) ar = M - 1;
      long boff = (long)(brow0 + row) * ldb + k0 + lc * 8;
      int ldst = row * BK + pc * 8;              // == c*8: linear dest
      GLD16(Ah + (long)ar * lda + k0 + lc * 8, Ash + ldst);
      if (AL) GLD16(Al + (long)ar * lda + k0 + lc * 8, Asl + ldst);
      GLD16(Bh + boff, Bsh + ldst);
      if (BL) GLD16(Bl + boff, Bsl + ldst);
    }
    __syncthreads();
#pragma unroll
    for (int kk = 0; kk < BK / 32; kk++) {
      const int ph = swz<BK>(lrow, kk * 4 + (l >> 4));
      short8 ah[4], al4[4], bh[4], bl4[4];
#pragma unroll
      for (int m = 0; m < 4; m++) {
        int ro = (wm * 64 + m * 16 + lrow) * BK + ph * 8;
        ah[m] = *(const short8*)(Ash + ro);
        if (AL) al4[m] = *(const short8*)(Asl + ro);
      }
#pragma unroll
      for (int n = 0; n < 4; n++) {
        int ro = (wn * 64 + n * 16 + lrow) * BK + ph * 8;
        bh[n] = *(const short8*)(Bsh + ro);
        if (BL) bl4[n] = *(const short8*)(Bsl + ro);
      }
#pragma unroll
      for (int m = 0; m < 4; m++)
#pragma unroll
        for (int n = 0; n < 4; n++) {
          acc[m][n] = __builtin_amdgcn_mfma_f32_16x16x32_bf16(ah[m], bh[n], acc[m][n], 0, 0, 0);
          if (BL)
            acc[m][n] = __builtin_amdgcn_mfma_f32_16x16x32_bf16(ah[m], bl4[n], acc[m][n], 0, 0, 0);
          if (AL)
            acc[m][n] = __builtin_amdgcn_mfma_f32_16x16x32_bf16(al4[m], bh[n], acc[m][n], 0, 0, 0);
        }
    }
  }

  const int orow0 = bm * 128 + wm * 64 + (l >> 4) * 4;
  const int ocol0 = bn * 128 + wn * 64 + lrow;
#pragma unroll
  for (int n = 0; n < 4; n++) {
    int gc = ocol0 + n * 16;
    float bv;
    if constexpr (ACC) bv = 0.f; else bv = bias[gc];
#pragma unroll
    for (int m = 0; m < 4; m++) {
#pragma unroll
      for (int ri = 0; ri < 4; ri++) {
        int gr = orow0 + m * 16 + ri;
        if (gr < M) {
          float v = acc[m][n][ri] + bv;
          if constexpr (ACC) v += Cf[(long)gr * ldc + gc];
          if constexpr (WMODE == 0) {
            Cf[(long)gr * ldc + gc] = v;
          } else {
            Chi[(long)gr * ldc + gc] = f2b(v);
            if constexpr (W8) C8[(long)gr * ldc + gc] = f2e4m3(v);
          }
        }
      }
    }
  }
}

// ---------------- host ----------------
extern "C" void kernel_launch(void* const* d_in, const int* in_sizes, int n_in,
                              void* d_out, int out_size, void* d_ws, size_t ws_size,
                              hipStream_t stream) {
  const float* x = (const float*)d_in[0];
  const int* ei = (const int*)d_in[1];
  const int E = in_sizes[1] / 2;
  const int* src = ei;
  const int* dst = ei + E;
  const float* in_w = (const float*)d_in[2];
  const float* in_b = (const float*)d_in[3];
  const float* w1 = (const float*)d_in[4];
  const float* b1 = (const float*)d_in[5];
  const float* ln_g = (const float*)d_in[6];
  const float* ln_b = (const float*)d_in[7];
  const float* w2 = (const float*)d_in[8];
  const float* b2 = (const float*)d_in[9];
  const float* w3 = (const float*)d_in[10];
  const float* b3 = (const float*)d_in[11];
  const float* out_w = (const float*)d_in[12];
  const float* out_b = (const float*)d_in[13];
  float* out = (float*)d_out;

  char* ws = (char*)d_ws;
  size_t off = 0;
  auto alloc = [&](size_t bytes) -> void* {
    void* p = ws + off;
    off += (bytes + 255) & ~(size_t)255;
    return p;
  };
  // ---- layout (~251 MB, ws is 256 MiB) ----
  int* rowptr = (int*)alloc((NN + 1) * 4);
  int* cursor = (int*)alloc((size_t)NN * 4);
  int* cols = (int*)alloc((size_t)E * 4);
  int* sums = (int*)alloc(1024);
  int* sums2 = (int*)alloc(256);
  unsigned short* in_wb_h = (unsigned short*)alloc((size_t)HD * DIN * 2);
  unsigned short* in_wb_l = (unsigned short*)alloc((size_t)HD * DIN * 2);
  unsigned short* w1b = (unsigned short*)alloc(2ul * DMID * DCAT * 2);
  unsigned short* w2b = (unsigned short*)alloc(2ul * DMID * DMID * 2);
  unsigned short* w3b = (unsigned short*)alloc(2ul * HD * DMID * 2);
  unsigned short* out_wb_h = (unsigned short*)alloc((size_t)DOUT * DSUM * 2);
  unsigned short* out_wb_l = (unsigned short*)alloc((size_t)DOUT * DSUM * 2);
  unsigned short* xpart = (unsigned short*)alloc((size_t)NN * DIN * 2);   // 25.6 MB
  unsigned short* h = (unsigned short*)alloc((size_t)NN * HD * 2);        // 51.2 MB
  unsigned char* h8 = (unsigned char*)alloc((size_t)NN * HD);             // 25.6 MB
  unsigned short* hpart = (unsigned short*)alloc((size_t)NN * HD * 2);    // 51.2 MB
  unsigned short* h1c = (unsigned short*)alloc((size_t)CH * DMID * 2);    // 39.3 MB
  unsigned short* h2c = (unsigned short*)alloc((size_t)CH * DMID * 2);    // 39.3 MB
  const size_t need = off;

  if (need > ws_size) {
    sentinel_fill<<<2048, 256, 0, stream>>>(out, (long)NN * DOUT, (float)ws_size);
    return;
  }

  // Aliases (dead-range reuse, safe by stream order):
  //  - x hi/lo split lives in hpart until first agg_h.
  //  - x8 fp8 copy lives in h1c until first GEMM1.
  unsigned short* xb_h = hpart;
  unsigned short* xb_l = hpart + (size_t)NN * DIN;
  unsigned char* x8 = (unsigned char*)h1c;

  hipMemsetAsync(rowptr, 0, (NN + 1) * 4, stream);
  hipMemsetAsync(cursor, 0, (size_t)NN * 4, stream);

  const int eb = (E + 255) / 256;
  const int nscan = NN + 1;
  const int nsb = (nscan + 255) / 256;

  deg_kernel<<<eb, 256, 0, stream>>>(dst, E, rowptr);
  scan_block<<<nsb, 256, 0, stream>>>(rowptr, nscan, sums);
  scan_block<<<1, 256, 0, stream>>>(sums, nsb, sums2);
  scan_add<<<nsb, 256, 0, stream>>>(rowptr, nscan, sums);
  fill_kernel<<<eb, 256, 0, stream>>>(src, dst, E, rowptr, cursor, cols);

  cast_split8_kernel<<<2048, 256, 0, stream>>>(x, xb_h, xb_l, x8, (long)NN * DIN / 4);
  cast_transpose_kernel<true><<<dim3(DIN / 32, HD / 32, 1), 256, 0, stream>>>(in_w, in_wb_h, in_wb_l, DIN, HD);
  cast_transpose_kernel<false><<<dim3(DCAT / 32, DMID / 32, 2), 256, 0, stream>>>(w1, w1b, nullptr, DCAT, DMID);
  cast_transpose_kernel<false><<<dim3(DMID / 32, DMID / 32, 2), 256, 0, stream>>>(w2, w2b, nullptr, DMID, DMID);
  cast_transpose_kernel<false><<<dim3(DMID / 32, HD / 32, 2), 256, 0, stream>>>(w3, w3b, nullptr, DMID, HD);
  cast_transpose_kernel<true><<<dim3(DSUM / 32, DOUT / 32, 1), 256, 0, stream>>>(out_w, out_wb_h, out_wb_l, DSUM, DOUT);

  const int MT = (NN + 127) / 128;  // 391
  const int AGB = NN / 4;           // 12500 blocks, wave-per-node

  // in_proj: h0 = bf16(x@in_w + in_b), + fp8 copy  (A hi/lo, B hi/lo: 3 passes, BK=64)
  gemmx<1, true, true, false, true, 2, 64><<<dim3(MT, HD / 128), 256, 0, stream>>>(
      xb_h, xb_l, DIN, in_wb_h, in_wb_l, DIN, in_b,
      nullptr, h, h8, HD, NN, DIN);

  // xpart = bf16(xb + A@x8)   (iteration-invariant; reads xb/x8 aliases)
  agg_x_kernel<<<AGB, 256, 0, stream>>>(xb_h, x8, rowptr, cols, xpart);

  // out = out_b + h0 @ out_w[0:512]   (B hi/lo: 2 passes, BK=64)
  gemmx<0, false, true, false, false, 2, 64><<<dim3(MT, DOUT / 128), 256, 0, stream>>>(
      h, nullptr, HD, out_wb_h, out_wb_l, DSUM, out_b,
      out, nullptr, nullptr, DOUT, NN, HD);

  for (int i = 0; i < 2; i++) {
    // hpart = bf16(h_i + A@h8_i)  (clobbers xb alias — xb dead by now)
    agg_h_kernel<<<AGB, 256, 0, stream>>>(h, h8, rowptr, cols, hpart);

    // MLP chunked over rows; GEMM3 writes h_{i+1} (+fp8) in place over h
    for (int r0 = 0; r0 < NN; r0 += CH) {
      int Mc = NN - r0 < CH ? NN - r0 : CH;
      int MTc = (Mc + 127) / 128;
      int MT8 = ((MTc + 7) / 8) * 8;
      // GEMM1: A split = [xpart | hpart], K=768, dbuf BK=32, swizzled
      gemm1p<false, false, 32><<<MT8 * (DMID / 128), 256, 0, stream>>>(
          xpart + (size_t)r0 * DIN, hpart + (size_t)r0 * HD, DIN, HD, DIN,
          w1b + (size_t)i * DMID * DCAT, DCAT,
          b1 + i * DMID, h1c, nullptr, DMID, Mc, DCAT, DMID / 128);
      ln_leaky_kernel<<<Mc, 256, 0, stream>>>(h1c, ln_g + i * DMID, ln_b + i * DMID);
      // GEMM2: fused leaky, dbuf BK=32, swizzled
      gemm1p<true, false, 32><<<MT8 * (DMID / 128), 256, 0, stream>>>(
          h1c, h1c, DMID, DMID, 1 << 30,
          w2b + (size_t)i * DMID * DMID, DMID,
          b2 + i * DMID, h2c, nullptr, DMID, Mc, DMID, DMID / 128);
      // GEMM3: writes h_{i+1} bf16 + fp8, dbuf BK=32, swizzled
      gemm1p<false, true, 32><<<MT8 * (HD / 128), 256, 0, stream>>>(
          h2c, h2c, DMID, DMID, 1 << 30,
          w3b + (size_t)i * HD * DMID, DMID,
          b3 + i * HD, h + (size_t)r0 * HD, h8 + (size_t)r0 * HD, HD, Mc, DMID, HD / 128);
    }

    // out += h_{i+1} @ out_w[512*(i+1) : 512*(i+2)]   (B hi/lo: 2 passes, BK=64)
    gemmx<0, false, true, true, false, 2, 64><<<dim3(MT, DOUT / 128), 256, 0, stream>>>(
        h, nullptr, HD,
        out_wb_h + (size_t)(i + 1) * HD, out_wb_l + (size_t)(i + 1) * HD, DSUM,
        nullptr, out, nullptr, nullptr, DOUT, NN, HD);
  }
}

// Round 15
// 1618.330 us; speedup vs baseline: 1.3533x; 1.0422x over previous
//
#include <hip/hip_runtime.h>
#include <hip/hip_bf16.h>

#define NN 50000
#define DIN 256
#define HD 512
#define DCAT 768
#define DMID 1024
#define DSUM 1536
#define DOUT 256
#define CH 19200
#define LN_EPS 1e-5f

typedef __attribute__((ext_vector_type(8))) short short8;
typedef __attribute__((ext_vector_type(4))) float f32x4;
typedef __attribute__((ext_vector_type(2))) float f32x2;

__device__ __forceinline__ unsigned short f2b(float f) {
  unsigned int u = __float_as_uint(f);
  u += 0x7FFF + ((u >> 16) & 1);   // round-to-nearest-even
  return (unsigned short)(u >> 16);
}
__device__ __forceinline__ float b2f(unsigned short s) {
  return __uint_as_float(((unsigned int)s) << 16);
}
__device__ __forceinline__ void splitbf(float v, unsigned short& hi, unsigned short& lo) {
  hi = f2b(v);
  lo = f2b(v - b2f(hi));
}
// fp8 e4m3 encode (hardware, saturating)
__device__ __forceinline__ unsigned char f2e4m3(float v) {
  return (unsigned char)(__builtin_amdgcn_cvt_pk_fp8_f32(v, v, 0, false) & 0xff);
}

// ---------------- diagnostic fill ----------------
__global__ void sentinel_fill(float* __restrict__ out, long n, float v) {
  for (long i = (long)blockIdx.x * blockDim.x + threadIdx.x; i < n;
       i += (long)gridDim.x * blockDim.x)
    out[i] = v;
}

// ---------------- casts / splits ----------------
// x -> bf16 hi/lo + fp8 in one pass
__global__ void cast_split8_kernel(const float* __restrict__ in,
                                   unsigned short* __restrict__ oh,
                                   unsigned short* __restrict__ ol,
                                   unsigned char* __restrict__ o8, long n4) {
  for (long i = (long)blockIdx.x * blockDim.x + threadIdx.x; i < n4;
       i += (long)gridDim.x * blockDim.x) {
    float4 v = ((const float4*)in)[i];
    ushort4 h, l;
    splitbf(v.x, h.x, l.x); splitbf(v.y, h.y, l.y);
    splitbf(v.z, h.z, l.z); splitbf(v.w, h.w, l.w);
    ((ushort4*)oh)[i] = h;
    ((ushort4*)ol)[i] = l;
    unsigned int r = __builtin_amdgcn_cvt_pk_fp8_f32(v.x, v.y, 0, false);
    r = __builtin_amdgcn_cvt_pk_fp8_f32(v.z, v.w, r, true);
    ((unsigned int*)o8)[i] = r;
  }
}

// in: [K][N] f32 -> out hi(/lo): [N][K] bf16  (K,N multiples of 32). blockIdx.z = matrix idx
template <bool SPLIT>
__global__ void cast_transpose_kernel(const float* __restrict__ in,
                                      unsigned short* __restrict__ oh,
                                      unsigned short* __restrict__ ol, int K, int N) {
  const float* src = in + (long)blockIdx.z * K * N;
  unsigned short* dh = oh + (long)blockIdx.z * K * N;
  unsigned short* dl = SPLIT ? ol + (long)blockIdx.z * K * N : nullptr;
  __shared__ unsigned short th[32][33];
  __shared__ unsigned short tl[SPLIT ? 32 : 1][33];
  int bk = blockIdx.x * 32, bn = blockIdx.y * 32;
  int tx = threadIdx.x & 31, ty = threadIdx.x >> 5;
#pragma unroll
  for (int i = ty; i < 32; i += 8) {
    float v = src[(long)(bk + i) * N + bn + tx];
    if (SPLIT) {
      unsigned short h, l;
      splitbf(v, h, l);
      th[i][tx] = h; tl[i][tx] = l;
    } else {
      th[i][tx] = f2b(v);
    }
  }
  __syncthreads();
#pragma unroll
  for (int i = ty; i < 32; i += 8) {
    dh[(long)(bn + i) * K + bk + tx] = th[tx][i];
    if (SPLIT) dl[(long)(bn + i) * K + bk + tx] = tl[tx][i];
  }
}

// ---------------- CSR build ----------------
__global__ void deg_kernel(const int* __restrict__ dst, int E, int* __restrict__ rowptr) {
  int i = blockIdx.x * blockDim.x + threadIdx.x;
  if (i < E) atomicAdd(&rowptr[dst[i] + 1], 1);
}

__global__ void scan_block(int* __restrict__ data, int n, int* __restrict__ sums) {
  __shared__ int tmp[2][256];
  int i = blockIdx.x * 256 + threadIdx.x;
  int v = (i < n) ? data[i] : 0;
  int pp = 0;
  tmp[0][threadIdx.x] = v;
  __syncthreads();
#pragma unroll
  for (int off = 1; off < 256; off <<= 1) {
    int t2 = tmp[pp][threadIdx.x];
    if (threadIdx.x >= off) t2 += tmp[pp][threadIdx.x - off];
    tmp[pp ^ 1][threadIdx.x] = t2;
    pp ^= 1;
    __syncthreads();
  }
  if (i < n) data[i] = tmp[pp][threadIdx.x];
  if (threadIdx.x == 255) sums[blockIdx.x] = tmp[pp][255];
}

__global__ void scan_add(int* __restrict__ data, int n, const int* __restrict__ sums) {
  int i = blockIdx.x * 256 + threadIdx.x;
  if (blockIdx.x > 0 && i < n) data[i] += sums[blockIdx.x - 1];
}

__global__ void fill_kernel(const int* __restrict__ src, const int* __restrict__ dst, int E,
                            const int* __restrict__ rowptr, int* __restrict__ cursor,
                            int* __restrict__ cols) {
  int i = blockIdx.x * blockDim.x + threadIdx.x;
  if (i < E) {
    int r = dst[i];
    int p = rowptr[r] + atomicAdd(&cursor[r], 1);
    cols[p] = src[i];
  }
}

// ---------------- aggregation (wave-per-node; fp8 neighbor gather; round-8 proven) ----------------
// xpart[i,:] = bf16(xb_i + sum_j x8_j)  (own bf16, neighbors fp8 256B/row)
__global__ void agg_x_kernel(const unsigned short* __restrict__ xb,
                             const unsigned char* __restrict__ x8,
                             const int* __restrict__ rowptr,
                             const int* __restrict__ cols,
                             unsigned short* __restrict__ xpart) {
  int node = blockIdx.x * 4 + (threadIdx.x >> 6);
  int lane = threadIdx.x & 63;
  ushort4 own = *((const ushort4*)(xb + (long)node * DIN) + lane);
  float s0 = b2f(own.x), s1 = b2f(own.y), s2 = b2f(own.z), s3 = b2f(own.w);
  int e0 = rowptr[node], e1 = rowptr[node + 1];
  int p = e0;
#define XACC(w)                                                   \
  {                                                               \
    f32x2 t0 = __builtin_amdgcn_cvt_pk_f32_fp8((w), false);       \
    f32x2 t1 = __builtin_amdgcn_cvt_pk_f32_fp8((w), true);        \
    s0 += t0.x; s1 += t0.y; s2 += t1.x; s3 += t1.y;               \
  }
  for (; p + 3 < e1; p += 4) {
    int j0 = cols[p], j1 = cols[p + 1], j2 = cols[p + 2], j3 = cols[p + 3];
    unsigned int a = *((const unsigned int*)(x8 + (long)j0 * DIN) + lane);
    unsigned int b = *((const unsigned int*)(x8 + (long)j1 * DIN) + lane);
    unsigned int c = *((const unsigned int*)(x8 + (long)j2 * DIN) + lane);
    unsigned int d = *((const unsigned int*)(x8 + (long)j3 * DIN) + lane);
    XACC(a); XACC(b); XACC(c); XACC(d);
  }
  for (; p < e1; p++) {
    unsigned int a = *((const unsigned int*)(x8 + (long)cols[p] * DIN) + lane);
    XACC(a);
  }
#undef XACC
  ushort4 o;
  o.x = f2b(s0); o.y = f2b(s1); o.z = f2b(s2); o.w = f2b(s3);
  *((ushort4*)(xpart + (long)node * DIN) + lane) = o;
}

// hpart[i,:] = bf16(h_i + sum_j h8_j)  (own bf16 1KB, neighbors fp8 512B/row)
__global__ void agg_h_kernel(const unsigned short* __restrict__ h,
                             const unsigned char* __restrict__ h8,
                             const int* __restrict__ rowptr, const int* __restrict__ cols,
                             unsigned short* __restrict__ hpart) {
  int node = blockIdx.x * 4 + (threadIdx.x >> 6);
  int lane = threadIdx.x & 63;
  short8 own = *((const short8*)(h + (long)node * HD) + lane);
  float s[8];
#pragma unroll
  for (int q = 0; q < 8; q++) s[q] = b2f((unsigned short)own[q]);
  int e0 = rowptr[node], e1 = rowptr[node + 1];
  int p = e0;
#define HACC(w)                                                   \
  {                                                               \
    f32x2 t0 = __builtin_amdgcn_cvt_pk_f32_fp8((w).x, false);     \
    f32x2 t1 = __builtin_amdgcn_cvt_pk_f32_fp8((w).x, true);      \
    f32x2 t2 = __builtin_amdgcn_cvt_pk_f32_fp8((w).y, false);     \
    f32x2 t3 = __builtin_amdgcn_cvt_pk_f32_fp8((w).y, true);      \
    s[0] += t0.x; s[1] += t0.y; s[2] += t1.x; s[3] += t1.y;       \
    s[4] += t2.x; s[5] += t2.y; s[6] += t3.x; s[7] += t3.y;       \
  }
  for (; p + 3 < e1; p += 4) {
    int j0 = cols[p], j1 = cols[p + 1], j2 = cols[p + 2], j3 = cols[p + 3];
    uint2 a = *((const uint2*)(h8 + (long)j0 * HD) + lane);
    uint2 b = *((const uint2*)(h8 + (long)j1 * HD) + lane);
    uint2 c = *((const uint2*)(h8 + (long)j2 * HD) + lane);
    uint2 d = *((const uint2*)(h8 + (long)j3 * HD) + lane);
    HACC(a); HACC(b); HACC(c); HACC(d);
  }
  for (; p < e1; p++) {
    uint2 a = *((const uint2*)(h8 + (long)cols[p] * HD) + lane);
    HACC(a);
  }
#undef HACC
  short8 o;
#pragma unroll
  for (int q = 0; q < 8; q++) o[q] = (short)f2b(s[q]);
  *((short8*)(hpart + (long)node * HD) + lane) = o;
}

// ---------------- LayerNorm + leaky on bf16 rows of width 1024 (in place) ----------------
__global__ void ln_leaky_kernel(unsigned short* __restrict__ arr,
                                const float* __restrict__ gamma,
                                const float* __restrict__ beta) {
  int row = blockIdx.x, t = threadIdx.x;
  unsigned short* p = arr + (long)row * DMID;
  ushort4 u = ((const ushort4*)p)[t];
  float v0 = b2f(u.x), v1 = b2f(u.y), v2 = b2f(u.z), v3 = b2f(u.w);
  float s = v0 + v1 + v2 + v3;
  float sq = v0 * v0 + v1 * v1 + v2 * v2 + v3 * v3;
#pragma unroll
  for (int off = 32; off >= 1; off >>= 1) {
    s += __shfl_down(s, off, 64);
    sq += __shfl_down(sq, off, 64);
  }
  __shared__ float red[8];
  int w = t >> 6, lane = t & 63;
  if (lane == 0) { red[w] = s; red[4 + w] = sq; }
  __syncthreads();
  s = red[0] + red[1] + red[2] + red[3];
  sq = red[4] + red[5] + red[6] + red[7];
  float mean = s * (1.f / DMID);
  float var = sq * (1.f / DMID) - mean * mean;
  float rstd = rsqrtf(var + LN_EPS);
  float4 gv = ((const float4*)gamma)[t];
  float4 bv = ((const float4*)beta)[t];
  float o0 = (v0 - mean) * rstd * gv.x + bv.x;
  float o1 = (v1 - mean) * rstd * gv.y + bv.y;
  float o2 = (v2 - mean) * rstd * gv.z + bv.z;
  float o3 = (v3 - mean) * rstd * gv.w + bv.w;
  o0 = o0 > 0.f ? o0 : 0.1f * o0;
  o1 = o1 > 0.f ? o1 : 0.1f * o1;
  o2 = o2 > 0.f ? o2 : 0.1f * o2;
  o3 = o3 > 0.f ? o3 : 0.1f * o3;
  ushort4 ou;
  ou.x = f2b(o0); ou.y = f2b(o1); ou.z = f2b(o2); ou.w = f2b(o3);
  ((ushort4*)p)[t] = ou;
}

#define GLD16(src, dst)                                                          \
  __builtin_amdgcn_global_load_lds(                                              \
      (const __attribute__((address_space(1))) void*)(src),                      \
      (__attribute__((address_space(3))) void*)(dst), 16, 0, 0)

// LDS chunk swizzle (chunk = 16B = 8 bf16). Rule #21: linear LDS dest via
// global_load_lds; the SOURCE address carries the inverse permutation; reads
// apply the same XOR. BK=64 rows (128B): ch ^ (row&7) -> 32 banks, 2-way.
// BK=32 rows (64B): ch ^ ((row>>1)&3) -> 2-way.
template <int BK>
__device__ __forceinline__ int swz(int row, int ch) {
  if constexpr (BK == 64) return ch ^ (row & 7);
  else return ch ^ ((row >> 1) & 3);
}

// ---------------- 1-pass conv GEMM: BK=64 single-buffer + T2 swizzle + repack epilogue ----------------
// 128x128 tile, 4 waves (2x2), OCC=3 (LDS 32KB stage / up to 52KB epilogue overlay).
// XCD-grouped 1-D grid. 32 MFMA per barrier-pair; conflict-free ds_reads.
template <bool ACT, bool W8, int BK>
__launch_bounds__(256, 3)
__global__ void gemm1p(const unsigned short* __restrict__ Ah,
                       const unsigned short* __restrict__ A2h,
                       int lda, int lda2, int ksplit,
                       const unsigned short* __restrict__ Bh,
                       int ldb, const float* __restrict__ bias,
                       unsigned short* __restrict__ Chi,
                       unsigned char* __restrict__ C8,
                       int ldc, int M, int K, int NT) {
  const int lin = blockIdx.x;
  const int xcd = lin & 7;
  const int seq = lin >> 3;
  const int bn = seq % NT;
  const int bm = xcd + 8 * (seq / NT);
  if (bm * 128 >= M) return;

  constexpr int CT_LD = 136;
  constexpr int TILE = 128 * BK;                 // elems per matrix
  constexpr int STAGE_B = 2 * TILE * 2;          // (A,B) x 2B single-buffer
  constexpr int CT_B = 128 * CT_LD * 2;
  constexpr int C8_B = W8 ? 128 * CT_LD : 0;
  constexpr int SMEM_B = (STAGE_B > CT_B + C8_B) ? STAGE_B : (CT_B + C8_B);
  __shared__ __align__(16) unsigned char smem[SMEM_B];
  unsigned short* Ash = (unsigned short*)smem;
  unsigned short* Bsh = Ash + TILE;
  const int t = threadIdx.x;
  const int l = t & 63;
  const int w = t >> 6;
  const int wm = w >> 1, wn = w & 1;
  const int lrow = l & 15;
  constexpr int CPR = BK / 8;                    // chunks per row

  f32x4 acc[4][4] = {};

  const int arow0 = bm * 128;
  const int brow0 = bn * 128;

  for (int k0 = 0; k0 < K; k0 += BK) {
    const bool first = k0 < ksplit;
    const unsigned short* Abase = first ? Ah : A2h;
    const int acol = first ? k0 : (k0 - ksplit);
    const int alda = first ? lda : lda2;
    __syncthreads();
#pragma unroll
    for (int it = 0; it < BK / 16; it++) {
      int c = t + it * 256;
      int row = c / CPR;
      int pc = c % CPR;
      int lc = swz<BK>(row, pc);                 // inverse-swizzled source chunk
      int ar = arow0 + row;
      if (ar >= M) ar = M - 1;
      int ldst = c * 8;                          // linear dest: lane*16B from wave base
      GLD16(Abase + (long)ar * alda + acol + lc * 8, Ash + ldst);
      GLD16(Bh + (long)(brow0 + row) * ldb + k0 + lc * 8, Bsh + ldst);
    }
    __syncthreads();
#pragma unroll
    for (int kk = 0; kk < BK / 32; kk++) {
      const int ph = swz<BK>(lrow, kk * 4 + (l >> 4));
      short8 ah[4], bh4[4];
#pragma unroll
      for (int m = 0; m < 4; m++)
        ah[m] = *(const short8*)(Ash + (wm * 64 + m * 16 + lrow) * BK + ph * 8);
#pragma unroll
      for (int n = 0; n < 4; n++)
        bh4[n] = *(const short8*)(Bsh + (wn * 64 + n * 16 + lrow) * BK + ph * 8);
#pragma unroll
      for (int m = 0; m < 4; m++)
#pragma unroll
        for (int n = 0; n < 4; n++)
          acc[m][n] = __builtin_amdgcn_mfma_f32_16x16x32_bf16(ah[m], bh4[n], acc[m][n], 0, 0, 0);
    }
  }

  // ---- epilogue: repack through LDS, then coalesced stores ----
  __syncthreads();
  unsigned short* Ct = (unsigned short*)smem;
  unsigned char* C8t = smem + CT_B;
  const int orl = wm * 64 + (l >> 4) * 4;
  const int ocl = wn * 64 + lrow;
#pragma unroll
  for (int n = 0; n < 4; n++) {
    float bv = bias[bn * 128 + ocl + n * 16];
#pragma unroll
    for (int m = 0; m < 4; m++) {
#pragma unroll
      for (int ri = 0; ri < 4; ri++) {
        float v = acc[m][n][ri] + bv;
        if constexpr (ACT) v = v > 0.f ? v : 0.1f * v;
        int rr = orl + m * 16 + ri, cc = ocl + n * 16;
        Ct[rr * CT_LD + cc] = f2b(v);
        if constexpr (W8) C8t[rr * CT_LD + cc] = f2e4m3(v);
      }
    }
  }
  __syncthreads();
  const long row0 = bm * 128;
  const long col0 = bn * 128;
#pragma unroll
  for (int p = 0; p < 8; p++) {
    int idx = t + p * 256;
    int r = idx >> 4, cb = (idx & 15) * 8;
    long gr = row0 + r;
    if (gr < M)
      *(short8*)(Chi + gr * ldc + col0 + cb) = *(const short8*)(Ct + r * CT_LD + cb);
  }
  if constexpr (W8) {
#pragma unroll
    for (int p = 0; p < 8; p++) {
      int idx = t + p * 256;
      int r = idx >> 4, cb = (idx & 15) * 8;
      long gr = row0 + r;
      if (gr < M)
        *(uint2*)(C8 + gr * ldc + col0 + cb) = *(const uint2*)(C8t + r * CT_LD + cb);
    }
  }
}

// ---------------- multi-pass MFMA GEMM (in_proj / out): 2-barrier + T2 swizzle ----------------
template <int WMODE, bool AL, bool BL, bool ACC, bool W8, int OCC, int BK>
__launch_bounds__(256, OCC)
__global__ void gemmx(const unsigned short* __restrict__ Ah,
                      const unsigned short* __restrict__ Al,
                      int lda,
                      const unsigned short* __restrict__ Bh,
                      const unsigned short* __restrict__ Bl,
                      int ldb, const float* __restrict__ bias,
                      float* __restrict__ Cf,
                      unsigned short* __restrict__ Chi,
                      unsigned char* __restrict__ C8,
                      int ldc, int M, int K) {
  __shared__ __align__(16) unsigned short Ash[128 * BK];
  __shared__ __align__(16) unsigned short Asl[AL ? 128 * BK : 16];
  __shared__ __align__(16) unsigned short Bsh[128 * BK];
  __shared__ __align__(16) unsigned short Bsl[BL ? 128 * BK : 16];
  const int t = threadIdx.x;
  const int bm = blockIdx.x, bn = blockIdx.y;
  const int l = t & 63;
  const int w = t >> 6;
  const int wm = w >> 1, wn = w & 1;
  const int lrow = l & 15;
  constexpr int CPR = BK / 8;

  f32x4 acc[4][4] = {};

  const int arow0 = bm * 128;
  const int brow0 = bn * 128;

  for (int k0 = 0; k0 < K; k0 += BK) {
    __syncthreads();
#pragma unroll
    for (int it = 0; it < BK / 16; it++) {
      int c = t + it * 256;
      int row = c / CPR;
      int pc = c % CPR;
      int lc = swz<BK>(row, pc);
      int ar = arow0 + row;
      if (ar >= M) ar = M - 1;
      long boff = (long)(brow0 + row) * ldb + k0 + lc * 8;
      int ldst = row * BK + pc * 8;              // == c*8: linear dest
      GLD16(Ah + (long)ar * lda + k0 + lc * 8, Ash + ldst);
      if (AL) GLD16(Al + (long)ar * lda + k0 + lc * 8, Asl + ldst);
      GLD16(Bh + boff, Bsh + ldst);
      if (BL) GLD16(Bl + boff, Bsl + ldst);
    }
    __syncthreads();
#pragma unroll
    for (int kk = 0; kk < BK / 32; kk++) {
      const int ph = swz<BK>(lrow, kk * 4 + (l >> 4));
      short8 ah[4], al4[4], bh[4], bl4[4];
#pragma unroll
      for (int m = 0; m < 4; m++) {
        int ro = (wm * 64 + m * 16 + lrow) * BK + ph * 8;
        ah[m] = *(const short8*)(Ash + ro);
        if (AL) al4[m] = *(const short8*)(Asl + ro);
      }
#pragma unroll
      for (int n = 0; n < 4; n++) {
        int ro = (wn * 64 + n * 16 + lrow) * BK + ph * 8;
        bh[n] = *(const short8*)(Bsh + ro);
        if (BL) bl4[n] = *(const short8*)(Bsl + ro);
      }
#pragma unroll
      for (int m = 0; m < 4; m++)
#pragma unroll
        for (int n = 0; n < 4; n++) {
          acc[m][n] = __builtin_amdgcn_mfma_f32_16x16x32_bf16(ah[m], bh[n], acc[m][n], 0, 0, 0);
          if (BL)
            acc[m][n] = __builtin_amdgcn_mfma_f32_16x16x32_bf16(ah[m], bl4[n], acc[m][n], 0, 0, 0);
          if (AL)
            acc[m][n] = __builtin_amdgcn_mfma_f32_16x16x32_bf16(al4[m], bh[n], acc[m][n], 0, 0, 0);
        }
    }
  }

  const int orow0 = bm * 128 + wm * 64 + (l >> 4) * 4;
  const int ocol0 = bn * 128 + wn * 64 + lrow;
#pragma unroll
  for (int n = 0; n < 4; n++) {
    int gc = ocol0 + n * 16;
    float bv;
    if constexpr (ACC) bv = 0.f; else bv = bias[gc];
#pragma unroll
    for (int m = 0; m < 4; m++) {
#pragma unroll
      for (int ri = 0; ri < 4; ri++) {
        int gr = orow0 + m * 16 + ri;
        if (gr < M) {
          float v = acc[m][n][ri] + bv;
          if constexpr (ACC) v += Cf[(long)gr * ldc + gc];
          if constexpr (WMODE == 0) {
            Cf[(long)gr * ldc + gc] = v;
          } else {
            Chi[(long)gr * ldc + gc] = f2b(v);
            if constexpr (W8) C8[(long)gr * ldc + gc] = f2e4m3(v);
          }
        }
      }
    }
  }
}

// ---------------- host ----------------
extern "C" void kernel_launch(void* const* d_in, const int* in_sizes, int n_in,
                              void* d_out, int out_size, void* d_ws, size_t ws_size,
                              hipStream_t stream) {
  const float* x = (const float*)d_in[0];
  const int* ei = (const int*)d_in[1];
  const int E = in_sizes[1] / 2;
  const int* src = ei;
  const int* dst = ei + E;
  const float* in_w = (const float*)d_in[2];
  const float* in_b = (const float*)d_in[3];
  const float* w1 = (const float*)d_in[4];
  const float* b1 = (const float*)d_in[5];
  const float* ln_g = (const float*)d_in[6];
  const float* ln_b = (const float*)d_in[7];
  const float* w2 = (const float*)d_in[8];
  const float* b2 = (const float*)d_in[9];
  const float* w3 = (const float*)d_in[10];
  const float* b3 = (const float*)d_in[11];
  const float* out_w = (const float*)d_in[12];
  const float* out_b = (const float*)d_in[13];
  float* out = (float*)d_out;

  char* ws = (char*)d_ws;
  size_t off = 0;
  auto alloc = [&](size_t bytes) -> void* {
    void* p = ws + off;
    off += (bytes + 255) & ~(size_t)255;
    return p;
  };
  // ---- layout (~251 MB, ws is 256 MiB) ----
  int* rowptr = (int*)alloc((NN + 1) * 4);
  int* cursor = (int*)alloc((size_t)NN * 4);
  int* cols = (int*)alloc((size_t)E * 4);
  int* sums = (int*)alloc(1024);
  int* sums2 = (int*)alloc(256);
  unsigned short* in_wb_h = (unsigned short*)alloc((size_t)HD * DIN * 2);
  unsigned short* in_wb_l = (unsigned short*)alloc((size_t)HD * DIN * 2);
  unsigned short* w1b = (unsigned short*)alloc(2ul * DMID * DCAT * 2);
  unsigned short* w2b = (unsigned short*)alloc(2ul * DMID * DMID * 2);
  unsigned short* w3b = (unsigned short*)alloc(2ul * HD * DMID * 2);
  unsigned short* out_wb_h = (unsigned short*)alloc((size_t)DOUT * DSUM * 2);
  unsigned short* out_wb_l = (unsigned short*)alloc((size_t)DOUT * DSUM * 2);
  unsigned short* xpart = (unsigned short*)alloc((size_t)NN * DIN * 2);   // 25.6 MB
  unsigned short* h = (unsigned short*)alloc((size_t)NN * HD * 2);        // 51.2 MB
  unsigned char* h8 = (unsigned char*)alloc((size_t)NN * HD);             // 25.6 MB
  unsigned short* hpart = (unsigned short*)alloc((size_t)NN * HD * 2);    // 51.2 MB
  unsigned short* h1c = (unsigned short*)alloc((size_t)CH * DMID * 2);    // 39.3 MB
  unsigned short* h2c = (unsigned short*)alloc((size_t)CH * DMID * 2);    // 39.3 MB
  const size_t need = off;

  if (need > ws_size) {
    sentinel_fill<<<2048, 256, 0, stream>>>(out, (long)NN * DOUT, (float)ws_size);
    return;
  }

  // Aliases (dead-range reuse, safe by stream order):
  //  - x hi/lo split lives in hpart until first agg_h.
  //  - x8 fp8 copy lives in h1c until first GEMM1.
  unsigned short* xb_h = hpart;
  unsigned short* xb_l = hpart + (size_t)NN * DIN;
  unsigned char* x8 = (unsigned char*)h1c;

  hipMemsetAsync(rowptr, 0, (NN + 1) * 4, stream);
  hipMemsetAsync(cursor, 0, (size_t)NN * 4, stream);

  const int eb = (E + 255) / 256;
  const int nscan = NN + 1;
  const int nsb = (nscan + 255) / 256;

  deg_kernel<<<eb, 256, 0, stream>>>(dst, E, rowptr);
  scan_block<<<nsb, 256, 0, stream>>>(rowptr, nscan, sums);
  scan_block<<<1, 256, 0, stream>>>(sums, nsb, sums2);
  scan_add<<<nsb, 256, 0, stream>>>(rowptr, nscan, sums);
  fill_kernel<<<eb, 256, 0, stream>>>(src, dst, E, rowptr, cursor, cols);

  cast_split8_kernel<<<2048, 256, 0, stream>>>(x, xb_h, xb_l, x8, (long)NN * DIN / 4);
  cast_transpose_kernel<true><<<dim3(DIN / 32, HD / 32, 1), 256, 0, stream>>>(in_w, in_wb_h, in_wb_l, DIN, HD);
  cast_transpose_kernel<false><<<dim3(DCAT / 32, DMID / 32, 2), 256, 0, stream>>>(w1, w1b, nullptr, DCAT, DMID);
  cast_transpose_kernel<false><<<dim3(DMID / 32, DMID / 32, 2), 256, 0, stream>>>(w2, w2b, nullptr, DMID, DMID);
  cast_transpose_kernel<false><<<dim3(DMID / 32, HD / 32, 2), 256, 0, stream>>>(w3, w3b, nullptr, DMID, HD);
  cast_transpose_kernel<true><<<dim3(DSUM / 32, DOUT / 32, 1), 256, 0, stream>>>(out_w, out_wb_h, out_wb_l, DSUM, DOUT);

  const int MT = (NN + 127) / 128;  // 391
  const int AGB = NN / 4;           // 12500 blocks, wave-per-node

  // in_proj: h0 = bf16(x@in_w + in_b), + fp8 copy  (A hi/lo, B hi/lo: 3 passes, BK=64)
  gemmx<1, true, true, false, true, 2, 64><<<dim3(MT, HD / 128), 256, 0, stream>>>(
      xb_h, xb_l, DIN, in_wb_h, in_wb_l, DIN, in_b,
      nullptr, h, h8, HD, NN, DIN);

  // xpart = bf16(xb + A@x8)   (iteration-invariant; reads xb/x8 aliases)
  agg_x_kernel<<<AGB, 256, 0, stream>>>(xb_h, x8, rowptr, cols, xpart);

  // out = out_b + h0 @ out_w[0:512]   (B hi/lo: 2 passes, BK=64)
  gemmx<0, false, true, false, false, 2, 64><<<dim3(MT, DOUT / 128), 256, 0, stream>>>(
      h, nullptr, HD, out_wb_h, out_wb_l, DSUM, out_b,
      out, nullptr, nullptr, DOUT, NN, HD);

  for (int i = 0; i < 2; i++) {
    // hpart = bf16(h_i + A@h8_i)  (clobbers xb alias — xb dead by now)
    agg_h_kernel<<<AGB, 256, 0, stream>>>(h, h8, rowptr, cols, hpart);

    // MLP chunked over rows; GEMM3 writes h_{i+1} (+fp8) in place over h
    for (int r0 = 0; r0 < NN; r0 += CH) {
      int Mc = NN - r0 < CH ? NN - r0 : CH;
      int MTc = (Mc + 127) / 128;
      int MT8 = ((MTc + 7) / 8) * 8;
      // GEMM1: A split = [xpart | hpart], K=768, BK=64 single-buf, swizzled
      gemm1p<false, false, 64><<<MT8 * (DMID / 128), 256, 0, stream>>>(
          xpart + (size_t)r0 * DIN, hpart + (size_t)r0 * HD, DIN, HD, DIN,
          w1b + (size_t)i * DMID * DCAT, DCAT,
          b1 + i * DMID, h1c, nullptr, DMID, Mc, DCAT, DMID / 128);
      ln_leaky_kernel<<<Mc, 256, 0, stream>>>(h1c, ln_g + i * DMID, ln_b + i * DMID);
      // GEMM2: fused leaky, BK=64 single-buf, swizzled
      gemm1p<true, false, 64><<<MT8 * (DMID / 128), 256, 0, stream>>>(
          h1c, h1c, DMID, DMID, 1 << 30,
          w2b + (size_t)i * DMID * DMID, DMID,
          b2 + i * DMID, h2c, nullptr, DMID, Mc, DMID, DMID / 128);
      // GEMM3: writes h_{i+1} bf16 + fp8, BK=64 single-buf, swizzled
      gemm1p<false, true, 64><<<MT8 * (HD / 128), 256, 0, stream>>>(
          h2c, h2c, DMID, DMID, 1 << 30,
          w3b + (size_t)i * HD * DMID, DMID,
          b3 + i * HD, h + (size_t)r0 * HD, h8 + (size_t)r0 * HD, HD, Mc, DMID, HD / 128);
    }

    // out += h_{i+1} @ out_w[512*(i+1) : 512*(i+2)]   (B hi/lo: 2 passes, BK=64)
    gemmx<0, false, true, true, false, 2, 64><<<dim3(MT, DOUT / 128), 256, 0, stream>>>(
        h, nullptr, HD,
        out_wb_h + (size_t)(i + 1) * HD, out_wb_l + (size_t)(i + 1) * HD, DSUM,
        nullptr, out, nullptr, nullptr, DOUT, NN, HD);
  }
}